// Round 1
// baseline (4082.305 us; speedup 1.0000x reference)
//
#include <hip/hip_runtime.h>

// VectorQuantize: argmin_k ||x - e_k||^2 then gather values[k].
// x: [16384][512] f32, codebook/values: [8192][512] f32, out: [16384][512] f32.
// f32-VALU compute-bound (no fp32 MFMA on CDNA4). Tiled register-blocked
// dot-product kernel with fused argmin + gather.

#define D      512
#define K      8192
#define NROWS  16384
#define BM     32     // rows per block
#define BN     64     // codes per K-chunk
#define BD     32     // d per stage
#define LDP    (BD + 4)   // 36 floats: 16B-aligned rows, 2-way-max bank aliasing

// ---- Kernel A: row sums of squares for x and codebook -----------------------
__global__ __launch_bounds__(256)
void sumsq_kernel(const float* __restrict__ x, const float* __restrict__ cb,
                  float* __restrict__ x_sq, float* __restrict__ e_sq) {
  int gwave = (blockIdx.x * 256 + threadIdx.x) >> 6;   // one wave per row
  int lane  = threadIdx.x & 63;
  const float* src;
  float* dst;
  if (gwave < NROWS) { src = x  + (size_t)gwave * D;          dst = x_sq + gwave; }
  else               { src = cb + (size_t)(gwave - NROWS) * D; dst = e_sq + (gwave - NROWS); }
  const float4* src4 = (const float4*)src;
  float s = 0.f;
#pragma unroll
  for (int i = 0; i < 2; ++i) {                        // 512 = 64 lanes * 2 * float4
    float4 v = src4[lane + i * 64];
    s += v.x * v.x + v.y * v.y + v.z * v.z + v.w * v.w;
  }
#pragma unroll
  for (int off = 32; off > 0; off >>= 1) s += __shfl_down(s, off, 64);
  if (lane == 0) *dst = s;
}

// ---- Kernel B: tiled dots + fused argmin + gather ---------------------------
__global__ __launch_bounds__(256, 2)
void vq_argmin_gather(const float* __restrict__ x, const float* __restrict__ cb,
                      const float* __restrict__ values,
                      const float* __restrict__ x_sq, const float* __restrict__ e_sq,
                      float* __restrict__ out) {
  __shared__ float x_lds[BM][LDP];
  __shared__ float e_lds[BN][LDP];
  __shared__ float red_d[BM][17];
  __shared__ int   red_i[BM][17];
  __shared__ int   bestk[BM];

  const int tid = threadIdx.x;
  const int tx  = tid & 15;      // code group: codes tx + 16*j
  const int ty  = tid >> 4;      // row group:  rows  ty*2 + i
  const int r0  = blockIdx.x * BM;
  const int row0 = ty * 2;

  float xsqr[2];
  xsqr[0] = x_sq[r0 + row0];
  xsqr[1] = x_sq[r0 + row0 + 1];

  float bd[2] = {3.4e38f, 3.4e38f};
  int   bi[2] = {0, 0};

  for (int kc = 0; kc < K; kc += BN) {
    float acc[2][4] = {{0.f, 0.f, 0.f, 0.f}, {0.f, 0.f, 0.f, 0.f}};

    for (int ds_ = 0; ds_ < D; ds_ += BD) {
      __syncthreads();
      // stage x tile: 32 rows x 32 d = 256 float4, 1 per thread
      {
        int row = tid >> 3, c4 = tid & 7;
        float4 v = *(const float4*)(x + (size_t)(r0 + row) * D + ds_ + c4 * 4);
        *(float4*)&x_lds[row][c4 * 4] = v;
      }
      // stage e tile: 64 codes x 32 d = 512 float4, 2 per thread
#pragma unroll
      for (int u = 0; u < 2; ++u) {
        int g = tid + u * 256;
        int er = g >> 3, ec4 = g & 7;
        float4 w = *(const float4*)(cb + (size_t)(kc + er) * D + ds_ + ec4 * 4);
        *(float4*)&e_lds[er][ec4 * 4] = w;
      }
      __syncthreads();

#pragma unroll
      for (int dg = 0; dg < BD; dg += 4) {
        float4 xv0 = *(const float4*)&x_lds[row0][dg];
        float4 xv1 = *(const float4*)&x_lds[row0 + 1][dg];
        float4 ev[4];
#pragma unroll
        for (int j = 0; j < 4; ++j) ev[j] = *(const float4*)&e_lds[tx + 16 * j][dg];
#pragma unroll
        for (int j = 0; j < 4; ++j) {
          acc[0][j] += xv0.x * ev[j].x; acc[0][j] += xv0.y * ev[j].y;
          acc[0][j] += xv0.z * ev[j].z; acc[0][j] += xv0.w * ev[j].w;
          acc[1][j] += xv1.x * ev[j].x; acc[1][j] += xv1.y * ev[j].y;
          acc[1][j] += xv1.z * ev[j].z; acc[1][j] += xv1.w * ev[j].w;
        }
      }
    }

    // score this chunk: dist = x_sq - 2*dot + e_sq  (mirrors reference formula)
#pragma unroll
    for (int j = 0; j < 4; ++j) {
      int code = kc + tx + 16 * j;
      float es = e_sq[code];
#pragma unroll
      for (int i = 0; i < 2; ++i) {
        float dist = xsqr[i] - 2.0f * acc[i][j] + es;
        if (dist < bd[i] || (dist == bd[i] && code < bi[i])) { bd[i] = dist; bi[i] = code; }
      }
    }
  }

  // block-level argmin across the 16 tx groups (first-index tie-break)
  __syncthreads();
#pragma unroll
  for (int i = 0; i < 2; ++i) { red_d[row0 + i][tx] = bd[i]; red_i[row0 + i][tx] = bi[i]; }
  __syncthreads();
  if (tid < BM) {
    float b = red_d[tid][0]; int idx = red_i[tid][0];
#pragma unroll
    for (int t = 1; t < 16; ++t) {
      float d2 = red_d[tid][t]; int i2 = red_i[tid][t];
      if (d2 < b || (d2 == b && i2 < idx)) { b = d2; idx = i2; }
    }
    bestk[tid] = idx;
  }
  __syncthreads();

  // fused gather: 32 rows x 128 float4, coalesced
#pragma unroll
  for (int u = 0; u < 16; ++u) {
    int f = u * 256 + tid;
    int row = f >> 7, q = f & 127;
    float4 v = *(const float4*)(values + (size_t)bestk[row] * D + q * 4);
    *(float4*)(out + (size_t)(r0 + row) * D + q * 4) = v;
  }
}

extern "C" void kernel_launch(void* const* d_in, const int* in_sizes, int n_in,
                              void* d_out, int out_size, void* d_ws, size_t ws_size,
                              hipStream_t stream) {
  const float* x      = (const float*)d_in[0];
  const float* cb     = (const float*)d_in[1];
  const float* values = (const float*)d_in[2];
  float* out  = (float*)d_out;
  float* x_sq = (float*)d_ws;              // 16384 f32
  float* e_sq = x_sq + NROWS;              // 8192 f32  (total 96 KB of ws)

  sumsq_kernel<<<(NROWS + K) / (256 / 64), 256, 0, stream>>>(x, cb, x_sq, e_sq);
  vq_argmin_gather<<<NROWS / BM, 256, 0, stream>>>(x, cb, values, x_sq, e_sq, out);
}

// Round 2
// 1957.401 us; speedup vs baseline: 2.0856x; 2.0856x over previous
//
#include <hip/hip_runtime.h>
#include <hip/hip_bf16.h>

// VectorQuantize via split-bf16 MFMA GEMM + exact f32 rescue.
// x: [16384][512] f32, codebook/values: [8192][512] f32, out: [16384][512] f32.
//
// Pipeline:
//  1. prep_split:   x -> Apack[16384][1024] bf16 = [hi|lo]; cb -> Bpack[8192][1024]
//  2. rowsumsq:     e_sq[8192] f32
//  3. vq_gemm_top2: dots = Apack . Bpack^T over K=2048-equiv (2 phases: B=eh dup, B=el dup)
//                   score = e_sq - 2*dot (x_sq row-constant, rank-invariant);
//                   per-row top-2 per 128-code tile -> cand[16384][64] records
//  4. vq_merge_rescore: global approx top-2, exact f32 rescore of both, argmin
//                   (np tie semantics), gather values[best] -> out.

#define D      512
#define M      16384
#define NCODE  8192
#define KP     1024
#define NB     64          // NCODE / 128

typedef float f32x4  __attribute__((ext_vector_type(4)));
typedef short bf16x8 __attribute__((ext_vector_type(8)));

#define FLT_BIG 3.402823466e38f

__device__ __forceinline__ void gload16(const __hip_bfloat16* g, __hip_bfloat16* l) {
  __builtin_amdgcn_global_load_lds(
      (const __attribute__((address_space(1))) void*)g,
      (__attribute__((address_space(3))) void*)l, 16, 0, 0);
}

__device__ __forceinline__ void top2_insert(float d, int i,
                                            float& d1, int& i1, float& d2, int& i2) {
  bool lt1 = (d < d1) || (d == d1 && i < i1);
  bool lt2 = (d < d2) || (d == d2 && i < i2);
  if (lt1) { d2 = d1; i2 = i1; d1 = d; i1 = i; }
  else if (lt2) { d2 = d; i2 = i; }
}

// ---- 1. split f32 -> [hi|lo] bf16 pack --------------------------------------
__global__ __launch_bounds__(256)
void prep_split(const float* __restrict__ src, __hip_bfloat16* __restrict__ pack,
                int nrows) {
  int total = nrows * (D / 4);
  for (int idx = blockIdx.x * 256 + threadIdx.x; idx < total; idx += gridDim.x * 256) {
    int r = idx >> 7, c4 = idx & 127;           // D/4 = 128
    float4 v = ((const float4*)src)[idx];
    float vv[4] = {v.x, v.y, v.z, v.w};
    ushort4 uh, ul;
    unsigned short* ph = (unsigned short*)&uh;
    unsigned short* pl = (unsigned short*)&ul;
#pragma unroll
    for (int j = 0; j < 4; ++j) {
      __hip_bfloat16 h = __float2bfloat16(vv[j]);
      float hf = __bfloat162float(h);
      __hip_bfloat16 lo = __float2bfloat16(vv[j] - hf);
      ph[j] = *(unsigned short*)&h;
      pl[j] = *(unsigned short*)&lo;
    }
    *(ushort4*)(pack + (size_t)r * KP + c4 * 4)       = uh;
    *(ushort4*)(pack + (size_t)r * KP + 512 + c4 * 4) = ul;
  }
}

// ---- 2. exact f32 row sum-of-squares ----------------------------------------
__global__ __launch_bounds__(256)
void rowsumsq(const float* __restrict__ src, float* __restrict__ dst, int nrows) {
  int gw = (blockIdx.x * 256 + threadIdx.x) >> 6;
  if (gw >= nrows) return;
  int lane = threadIdx.x & 63;
  const float4* s4 = (const float4*)(src + (size_t)gw * D);
  float s = 0.f;
#pragma unroll
  for (int i = 0; i < 2; ++i) {
    float4 v = s4[lane + i * 64];
    s += v.x * v.x + v.y * v.y + v.z * v.z + v.w * v.w;
  }
#pragma unroll
  for (int off = 32; off > 0; off >>= 1) s += __shfl_down(s, off, 64);
  if (lane == 0) dst[gw] = s;
}

// ---- 3. MFMA GEMM (m97 128^2 structure) + fused per-tile top-2 --------------
__global__ __launch_bounds__(256, 2)
void vq_gemm_top2(const __hip_bfloat16* __restrict__ Apack,
                  const __hip_bfloat16* __restrict__ Bpack,
                  const float* __restrict__ e_sq,
                  float4* __restrict__ cand) {
  __shared__ __hip_bfloat16 As[128 * 32];   // 8 KB, 16B-granule col-major: g = c16*128+row
  __shared__ __hip_bfloat16 Bs[128 * 32];   // 8 KB
  __shared__ float  esh[128];
  __shared__ float4 red[128][2];            // 4 KB

  const int tid = threadIdx.x;
  const int w = tid >> 6, l = tid & 63;
  const int wr = w >> 1, wc = w & 1;
  const int lr = l & 15, lh = l >> 4;

  // XCD-aware bijective swizzle (8192 % 8 == 0)
  int bid = blockIdx.x;
  int s = (bid & 7) * 1024 + (bid >> 3);
  int mt = s >> 6, nt = s & 63;
  const int row0 = mt * 128, col0 = nt * 128;

  if (tid < 128) esh[tid] = e_sq[col0 + tid];

  f32x4 acc[4][4] = {};

  // staging geometry: granule f in [0,512): row = f&127, c16 = f>>7
  const int f0 = tid, f1 = tid + 256;
  const int ra0 = f0 & 127, ca0 = f0 >> 7;
  const int ra1 = f1 & 127, ca1 = f1 >> 7;

#pragma unroll 1
  for (int p = 0; p < 2; ++p) {
    const int bcol = p * 512;
#pragma unroll 1
    for (int k = 0; k < 1024; k += 32) {
      __syncthreads();
      gload16(Apack + (size_t)(row0 + ra0) * KP + k + ca0 * 8, As + f0 * 8);
      gload16(Apack + (size_t)(row0 + ra1) * KP + k + ca1 * 8, As + f1 * 8);
      gload16(Bpack + (size_t)(col0 + ra0) * KP + bcol + (k & 511) + ca0 * 8, Bs + f0 * 8);
      gload16(Bpack + (size_t)(col0 + ra1) * KP + bcol + (k & 511) + ca1 * 8, Bs + f1 * 8);
      __syncthreads();

      const bf16x8* Ag = (const bf16x8*)As;
      const bf16x8* Bg = (const bf16x8*)Bs;
      bf16x8 a[4], b[4];
#pragma unroll
      for (int m = 0; m < 4; ++m) a[m] = Ag[lh * 128 + wr * 64 + m * 16 + lr];
#pragma unroll
      for (int n = 0; n < 4; ++n) b[n] = Bg[lh * 128 + wc * 64 + n * 16 + lr];
#pragma unroll
      for (int m = 0; m < 4; ++m)
#pragma unroll
        for (int n = 0; n < 4; ++n)
          acc[m][n] = __builtin_amdgcn_mfma_f32_16x16x32_bf16(a[m], b[n], acc[m][n], 0, 0, 0);
    }
  }

  // ---- epilogue: per-row top-2 of approx score within this 128x128 tile ----
#pragma unroll
  for (int m = 0; m < 4; ++m) {
#pragma unroll
    for (int q = 0; q < 4; ++q) {
      float d1 = FLT_BIG, d2 = FLT_BIG;
      int   i1 = 0x7fffffff, i2 = 0x7fffffff;
#pragma unroll
      for (int n = 0; n < 4; ++n) {
        int cl = wc * 64 + n * 16 + lr;
        float sc = esh[cl] - 2.0f * acc[m][n][q];
        top2_insert(sc, col0 + cl, d1, i1, d2, i2);
      }
#pragma unroll
      for (int s2 = 1; s2 < 16; s2 <<= 1) {
        float od1 = __shfl_xor(d1, s2, 64); int oi1 = __shfl_xor(i1, s2, 64);
        float od2 = __shfl_xor(d2, s2, 64); int oi2 = __shfl_xor(i2, s2, 64);
        top2_insert(od1, oi1, d1, i1, d2, i2);
        top2_insert(od2, oi2, d1, i1, d2, i2);
      }
      if (lr == 0)
        red[wr * 64 + m * 16 + lh * 4 + q][wc] =
            make_float4(d1, __int_as_float(i1), d2, __int_as_float(i2));
    }
  }
  __syncthreads();
  if (tid < 128) {
    float4 r0 = red[tid][0], r1 = red[tid][1];
    float d1 = r0.x; int i1 = __float_as_int(r0.y);
    float d2 = r0.z; int i2 = __float_as_int(r0.w);
    top2_insert(r1.x, __float_as_int(r1.y), d1, i1, d2, i2);
    top2_insert(r1.z, __float_as_int(r1.w), d1, i1, d2, i2);
    cand[(size_t)(row0 + tid) * NB + nt] =
        make_float4(d1, __int_as_float(i1), d2, __int_as_float(i2));
  }
}

// ---- 4. merge candidates, exact f32 rescore, gather -------------------------
__global__ __launch_bounds__(256)
void vq_merge_rescore(const float* __restrict__ x, const float* __restrict__ cb,
                      const float* __restrict__ values, const float* __restrict__ e_sq,
                      const float4* __restrict__ cand, float* __restrict__ out) {
  int row = blockIdx.x * 4 + (threadIdx.x >> 6);
  int l = threadIdx.x & 63;

  float4 rec = cand[(size_t)row * NB + l];
  float d1 = rec.x; int i1 = __float_as_int(rec.y);
  float d2 = rec.z; int i2 = __float_as_int(rec.w);
#pragma unroll
  for (int s2 = 1; s2 < 64; s2 <<= 1) {
    float od1 = __shfl_xor(d1, s2, 64); int oi1 = __shfl_xor(i1, s2, 64);
    float od2 = __shfl_xor(d2, s2, 64); int oi2 = __shfl_xor(i2, s2, 64);
    top2_insert(od1, oi1, d1, i1, d2, i2);
    top2_insert(od2, oi2, d1, i1, d2, i2);
  }

  // exact f32 rescore of the two candidates (deterministic reduction order)
  const float4* xr = (const float4*)(x + (size_t)row * D);
  const float4* c1 = (const float4*)(cb + (size_t)i1 * D);
  const float4* c2 = (const float4*)(cb + (size_t)i2 * D);
  float xsq = 0.f, dt1 = 0.f, dt2 = 0.f;
#pragma unroll
  for (int u = 0; u < 2; ++u) {
    float4 xv = xr[l + 64 * u], a = c1[l + 64 * u], b = c2[l + 64 * u];
    xsq += xv.x * xv.x + xv.y * xv.y + xv.z * xv.z + xv.w * xv.w;
    dt1 += xv.x * a.x + xv.y * a.y + xv.z * a.z + xv.w * a.w;
    dt2 += xv.x * b.x + xv.y * b.y + xv.z * b.z + xv.w * b.w;
  }
#pragma unroll
  for (int s2 = 1; s2 < 64; s2 <<= 1) {
    xsq += __shfl_xor(xsq, s2, 64);
    dt1 += __shfl_xor(dt1, s2, 64);
    dt2 += __shfl_xor(dt2, s2, 64);
  }
  float D1 = xsq - 2.0f * dt1 + e_sq[i1];
  float D2 = xsq - 2.0f * dt2 + e_sq[i2];
  int best = (D2 < D1 || (D2 == D1 && i2 < i1)) ? i2 : i1;

  const float4* vsrc = (const float4*)(values + (size_t)best * D);
  float4* dst = (float4*)(out + (size_t)row * D);
  dst[l] = vsrc[l];
  dst[l + 64] = vsrc[l + 64];
}

// ======================= fallback (R1 f32-VALU path) =========================
#define BM 32
#define BN 64
#define BD 32
#define LDP (BD + 4)

__global__ __launch_bounds__(256)
void sumsq_kernel(const float* __restrict__ x, const float* __restrict__ cb,
                  float* __restrict__ x_sq, float* __restrict__ e_sq) {
  int gwave = (blockIdx.x * 256 + threadIdx.x) >> 6;
  int lane  = threadIdx.x & 63;
  const float* src; float* dst;
  if (gwave < M) { src = x + (size_t)gwave * D; dst = x_sq + gwave; }
  else           { src = cb + (size_t)(gwave - M) * D; dst = e_sq + (gwave - M); }
  const float4* src4 = (const float4*)src;
  float s = 0.f;
#pragma unroll
  for (int i = 0; i < 2; ++i) {
    float4 v = src4[lane + i * 64];
    s += v.x * v.x + v.y * v.y + v.z * v.z + v.w * v.w;
  }
#pragma unroll
  for (int off = 32; off > 0; off >>= 1) s += __shfl_down(s, off, 64);
  if (lane == 0) *dst = s;
}

__global__ __launch_bounds__(256, 2)
void vq_argmin_gather(const float* __restrict__ x, const float* __restrict__ cb,
                      const float* __restrict__ values,
                      const float* __restrict__ x_sq, const float* __restrict__ e_sq,
                      float* __restrict__ out) {
  __shared__ float x_lds[BM][LDP];
  __shared__ float e_lds[BN][LDP];
  __shared__ float red_d[BM][17];
  __shared__ int   red_i[BM][17];
  __shared__ int   bestk[BM];
  const int tid = threadIdx.x;
  const int tx = tid & 15, ty = tid >> 4;
  const int r0 = blockIdx.x * BM, row0 = ty * 2;
  float xsqr[2] = {x_sq[r0 + row0], x_sq[r0 + row0 + 1]};
  float bd[2] = {FLT_BIG, FLT_BIG};
  int bi[2] = {0, 0};
  for (int kc = 0; kc < NCODE; kc += BN) {
    float acc[2][4] = {{0.f,0.f,0.f,0.f},{0.f,0.f,0.f,0.f}};
    for (int ds_ = 0; ds_ < D; ds_ += BD) {
      __syncthreads();
      { int row = tid >> 3, c4 = tid & 7;
        *(float4*)&x_lds[row][c4*4] = *(const float4*)(x + (size_t)(r0+row)*D + ds_ + c4*4); }
#pragma unroll
      for (int u = 0; u < 2; ++u) {
        int g = tid + u * 256, er = g >> 3, ec4 = g & 7;
        *(float4*)&e_lds[er][ec4*4] = *(const float4*)(cb + (size_t)(kc+er)*D + ds_ + ec4*4);
      }
      __syncthreads();
#pragma unroll
      for (int dg = 0; dg < BD; dg += 4) {
        float4 xv0 = *(const float4*)&x_lds[row0][dg];
        float4 xv1 = *(const float4*)&x_lds[row0+1][dg];
        float4 ev[4];
#pragma unroll
        for (int j = 0; j < 4; ++j) ev[j] = *(const float4*)&e_lds[tx + 16*j][dg];
#pragma unroll
        for (int j = 0; j < 4; ++j) {
          acc[0][j] += xv0.x*ev[j].x; acc[0][j] += xv0.y*ev[j].y;
          acc[0][j] += xv0.z*ev[j].z; acc[0][j] += xv0.w*ev[j].w;
          acc[1][j] += xv1.x*ev[j].x; acc[1][j] += xv1.y*ev[j].y;
          acc[1][j] += xv1.z*ev[j].z; acc[1][j] += xv1.w*ev[j].w;
        }
      }
    }
#pragma unroll
    for (int j = 0; j < 4; ++j) {
      int code = kc + tx + 16*j;
      float es = e_sq[code];
#pragma unroll
      for (int i = 0; i < 2; ++i) {
        float dist = xsqr[i] - 2.0f*acc[i][j] + es;
        if (dist < bd[i] || (dist == bd[i] && code < bi[i])) { bd[i] = dist; bi[i] = code; }
      }
    }
  }
  __syncthreads();
#pragma unroll
  for (int i = 0; i < 2; ++i) { red_d[row0+i][tx] = bd[i]; red_i[row0+i][tx] = bi[i]; }
  __syncthreads();
  if (tid < BM) {
    float b = red_d[tid][0]; int idx = red_i[tid][0];
#pragma unroll
    for (int t = 1; t < 16; ++t) {
      float dd = red_d[tid][t]; int ii = red_i[tid][t];
      if (dd < b || (dd == b && ii < idx)) { b = dd; idx = ii; }
    }
    bestk[tid] = idx;
  }
  __syncthreads();
#pragma unroll
  for (int u = 0; u < 16; ++u) {
    int f = u * 256 + tid, row = f >> 7, q = f & 127;
    *(float4*)(out + (size_t)(r0+row)*D + q*4) =
        *(const float4*)(values + (size_t)bestk[row]*D + q*4);
  }
}

// ============================================================================
extern "C" void kernel_launch(void* const* d_in, const int* in_sizes, int n_in,
                              void* d_out, int out_size, void* d_ws, size_t ws_size,
                              hipStream_t stream) {
  const float* x      = (const float*)d_in[0];
  const float* cb     = (const float*)d_in[1];
  const float* values = (const float*)d_in[2];
  float* out = (float*)d_out;

  const size_t A_BYTES = (size_t)M * KP * 2;        // 32 MB
  const size_t B_BYTES = (size_t)NCODE * KP * 2;    // 16 MB
  const size_t C_BYTES = (size_t)M * NB * 16;       // 16 MB
  const size_t E_BYTES = (size_t)NCODE * 4;         // 32 KB
  const size_t NEED = A_BYTES + B_BYTES + C_BYTES + E_BYTES;

  if (ws_size >= NEED) {
    char* base = (char*)d_ws;
    __hip_bfloat16* Apack = (__hip_bfloat16*)base;
    __hip_bfloat16* Bpack = (__hip_bfloat16*)(base + A_BYTES);
    float4* cand = (float4*)(base + A_BYTES + B_BYTES);
    float* e_sq  = (float*)(base + A_BYTES + B_BYTES + C_BYTES);

    prep_split<<<2048, 256, 0, stream>>>(x, Apack, M);
    prep_split<<<1024, 256, 0, stream>>>(cb, Bpack, NCODE);
    rowsumsq<<<NCODE / 4, 256, 0, stream>>>(cb, e_sq, NCODE);
    vq_gemm_top2<<<(M / 128) * NB, 256, 0, stream>>>(Apack, Bpack, e_sq, cand);
    vq_merge_rescore<<<M / 4, 256, 0, stream>>>(x, cb, values, e_sq, cand, out);
  } else {
    float* x_sq = (float*)d_ws;
    float* e_sq = x_sq + M;
    sumsq_kernel<<<(M + NCODE) / 4, 256, 0, stream>>>(x, cb, x_sq, e_sq);
    vq_argmin_gather<<<M / BM, 256, 0, stream>>>(x, cb, values, x_sq, e_sq, out);
  }
}

// Round 3
// 1314.248 us; speedup vs baseline: 3.1062x; 1.4894x over previous
//
#include <hip/hip_runtime.h>
#include <hip/hip_bf16.h>

// VectorQuantize: argmin_k ||x - e_k||^2 then gather values[k].
// R3: hi-bf16-only candidate GEMM (K=512) with 2-deep counted-vmcnt prefetch
// (3 LDS buffers, never drain in-loop), L2-aware XCD block ordering, per-tile
// top-2 -> global top-4 -> exact f32 rescore (np tie semantics) -> gather.

#define D      512
#define M      16384
#define NCODE  8192
#define KH     512         // hi-only packed K
#define NB     64          // NCODE / 128 tiles per row
#define NSTEP  16          // KH / 32

typedef float f32x4  __attribute__((ext_vector_type(4)));
typedef short bf16x8 __attribute__((ext_vector_type(8)));

#define FLT_BIG 3.402823466e38f

__device__ __forceinline__ void gload16(const __hip_bfloat16* g, __hip_bfloat16* l) {
  __builtin_amdgcn_global_load_lds(
      (const __attribute__((address_space(1))) void*)g,
      (__attribute__((address_space(3))) void*)l, 16, 0, 0);
}

__device__ __forceinline__ void top2_insert(float d, int i,
                                            float& d1, int& i1, float& d2, int& i2) {
  bool lt1 = (d < d1) || (d == d1 && i < i1);
  bool lt2 = (d < d2) || (d == d2 && i < i2);
  if (lt1) { d2 = d1; i2 = i1; d1 = d; i1 = i; }
  else if (lt2) { d2 = d; i2 = i; }
}

__device__ __forceinline__ void top4_insert(float nd, int ni,
    float& d0, int& i0, float& d1, int& i1,
    float& d2, int& i2, float& d3, int& i3) {
  bool l0 = (nd < d0) || (nd == d0 && ni < i0);
  bool l1 = (nd < d1) || (nd == d1 && ni < i1);
  bool l2 = (nd < d2) || (nd == d2 && ni < i2);
  bool l3 = (nd < d3) || (nd == d3 && ni < i3);
  if (l0)      { d3 = d2; i3 = i2; d2 = d1; i2 = i1; d1 = d0; i1 = i0; d0 = nd; i0 = ni; }
  else if (l1) { d3 = d2; i3 = i2; d2 = d1; i2 = i1; d1 = nd; i1 = ni; }
  else if (l2) { d3 = d2; i3 = i2; d2 = nd; i2 = ni; }
  else if (l3) { d3 = nd; i3 = ni; }
}

// ---- 1. f32 -> hi-bf16 pack -------------------------------------------------
__global__ __launch_bounds__(256)
void prep_hi(const float* __restrict__ src, __hip_bfloat16* __restrict__ pack,
             int nrows) {
  int total = nrows * (D / 4);
  for (int idx = blockIdx.x * 256 + threadIdx.x; idx < total; idx += gridDim.x * 256) {
    float4 v = ((const float4*)src)[idx];
    float vv[4] = {v.x, v.y, v.z, v.w};
    ushort4 uh;
    unsigned short* ph = (unsigned short*)&uh;
#pragma unroll
    for (int j = 0; j < 4; ++j) {
      __hip_bfloat16 h = __float2bfloat16(vv[j]);   // round-to-nearest-even
      ph[j] = *(unsigned short*)&h;
    }
    ((ushort4*)pack)[idx] = uh;
  }
}

// ---- 2. exact f32 row sum-of-squares (codebook) -----------------------------
__global__ __launch_bounds__(256)
void rowsumsq(const float* __restrict__ src, float* __restrict__ dst, int nrows) {
  int gw = (blockIdx.x * 256 + threadIdx.x) >> 6;
  if (gw >= nrows) return;
  int lane = threadIdx.x & 63;
  const float4* s4 = (const float4*)(src + (size_t)gw * D);
  float s = 0.f;
#pragma unroll
  for (int i = 0; i < 2; ++i) {
    float4 v = s4[lane + i * 64];
    s += v.x * v.x + v.y * v.y + v.z * v.z + v.w * v.w;
  }
#pragma unroll
  for (int off = 32; off > 0; off >>= 1) s += __shfl_down(s, off, 64);
  if (lane == 0) dst[gw] = s;
}

// ---- 3. hi-bf16 MFMA GEMM, 2-deep prefetch, fused per-tile top-2 ------------
__global__ __launch_bounds__(256, 3)
void vq_gemm_top2(const __hip_bfloat16* __restrict__ Ahi,
                  const __hip_bfloat16* __restrict__ Bhi,
                  const float* __restrict__ e_sq,
                  float4* __restrict__ cand) {
  __shared__ __hip_bfloat16 As[3][128 * 32];   // 3 x 8 KB
  __shared__ __hip_bfloat16 Bs[3][128 * 32];   // 3 x 8 KB
  __shared__ float4 red[128][2];               // 4 KB

  const int tid = threadIdx.x;
  const int w = tid >> 6, l = tid & 63;
  const int wr = w >> 1, wc = w & 1;
  const int lr = l & 15, lh = l >> 4;

  // L2-aware XCD ordering: per XCD, 8-nt groups, nt fastest within an mt sweep.
  // XCD working set: 8 B-panels (1 MB) + ~12 A-panels (1.5 MB) < 4 MB L2.
  const int bid = blockIdx.x;
  const int xcd = bid & 7, idx = bid >> 3;     // 1024 blocks per XCD
  const int g = idx >> 7;                      // 8 nt-groups of 8
  const int rem = idx & 127;
  const int mtl = rem >> 3, ntl = rem & 7;
  const int mt = xcd * 16 + mtl;               // 128 m-tiles
  const int nt = g * 8 + ntl;                  // 64 n-tiles
  const int row0 = mt * 128, col0 = nt * 128;

  f32x4 acc[4][4] = {};

  // staging geometry: granule f in [0,512): row = f&127, k16 = f>>7
  const int f0 = tid, f1 = tid + 256;
  const int ra0 = f0 & 127, ka0 = f0 >> 7;
  const int ra1 = f1 & 127, ka1 = f1 >> 7;

#define STAGE(buf, t)                                                          \
  do {                                                                         \
    const int kk = (t) * 32;                                                   \
    gload16(Ahi + (size_t)(row0 + ra0) * KH + kk + ka0 * 8, As[(buf)] + f0 * 8); \
    gload16(Ahi + (size_t)(row0 + ra1) * KH + kk + ka1 * 8, As[(buf)] + f1 * 8); \
    gload16(Bhi + (size_t)(col0 + ra0) * KH + kk + ka0 * 8, Bs[(buf)] + f0 * 8); \
    gload16(Bhi + (size_t)(col0 + ra1) * KH + kk + ka1 * 8, Bs[(buf)] + f1 * 8); \
  } while (0)

  STAGE(0, 0);
  STAGE(1, 1);

#pragma unroll
  for (int t = 0; t < NSTEP; ++t) {
    if (t + 2 < NSTEP) STAGE((t + 2) % 3, t + 2);
    // counted wait: leave future tiles' loads (4 each) in flight
    if (t + 2 < NSTEP)      asm volatile("s_waitcnt vmcnt(8)" ::: "memory");
    else if (t + 1 < NSTEP) asm volatile("s_waitcnt vmcnt(4)" ::: "memory");
    else                    asm volatile("s_waitcnt vmcnt(0)" ::: "memory");
    __builtin_amdgcn_s_barrier();
    asm volatile("" ::: "memory");   // no ds_read hoist above barrier

    const bf16x8* Ag = (const bf16x8*)As[t % 3];
    const bf16x8* Bg = (const bf16x8*)Bs[t % 3];
    bf16x8 a[4], b[4];
#pragma unroll
    for (int m = 0; m < 4; ++m) a[m] = Ag[lh * 128 + wr * 64 + m * 16 + lr];
#pragma unroll
    for (int n = 0; n < 4; ++n) b[n] = Bg[lh * 128 + wc * 64 + n * 16 + lr];
#pragma unroll
    for (int m = 0; m < 4; ++m)
#pragma unroll
      for (int n = 0; n < 4; ++n)
        acc[m][n] = __builtin_amdgcn_mfma_f32_16x16x32_bf16(a[m], b[n], acc[m][n], 0, 0, 0);

    asm volatile("" ::: "memory");
    __builtin_amdgcn_s_barrier();    // all waves done reading buf[t%3]
  }
#undef STAGE

  // ---- epilogue: per-row top-2 of approx score within this 128x128 tile ----
  float es[4];
#pragma unroll
  for (int n = 0; n < 4; ++n) es[n] = e_sq[col0 + wc * 64 + n * 16 + lr];

#pragma unroll
  for (int m = 0; m < 4; ++m) {
#pragma unroll
    for (int q = 0; q < 4; ++q) {
      float d1 = FLT_BIG, d2 = FLT_BIG;
      int   i1 = 0x7fffffff, i2 = 0x7fffffff;
#pragma unroll
      for (int n = 0; n < 4; ++n) {
        int cl = wc * 64 + n * 16 + lr;
        float sc = es[n] - 2.0f * acc[m][n][q];
        top2_insert(sc, col0 + cl, d1, i1, d2, i2);
      }
#pragma unroll
      for (int s2 = 1; s2 < 16; s2 <<= 1) {
        float od1 = __shfl_xor(d1, s2, 64); int oi1 = __shfl_xor(i1, s2, 64);
        float od2 = __shfl_xor(d2, s2, 64); int oi2 = __shfl_xor(i2, s2, 64);
        top2_insert(od1, oi1, d1, i1, d2, i2);
        top2_insert(od2, oi2, d1, i1, d2, i2);
      }
      if (lr == 0)
        red[wr * 64 + m * 16 + lh * 4 + q][wc] =
            make_float4(d1, __int_as_float(i1), d2, __int_as_float(i2));
    }
  }
  __syncthreads();
  if (tid < 128) {
    float4 r0 = red[tid][0], r1 = red[tid][1];
    float d1 = r0.x; int i1 = __float_as_int(r0.y);
    float d2 = r0.z; int i2 = __float_as_int(r0.w);
    top2_insert(r1.x, __float_as_int(r1.y), d1, i1, d2, i2);
    top2_insert(r1.z, __float_as_int(r1.w), d1, i1, d2, i2);
    cand[(size_t)(row0 + tid) * NB + nt] =
        make_float4(d1, __int_as_float(i1), d2, __int_as_float(i2));
  }
}

// ---- 4. global top-4, exact f32 rescore, gather -----------------------------
__global__ __launch_bounds__(256)
void vq_merge_rescore(const float* __restrict__ x, const float* __restrict__ cb,
                      const float* __restrict__ values, const float* __restrict__ e_sq,
                      const float4* __restrict__ cand, float* __restrict__ out) {
  int row = blockIdx.x * 4 + (threadIdx.x >> 6);
  int l = threadIdx.x & 63;

  float4 rec = cand[(size_t)row * NB + l];      // lane l: tile l's (d1<=d2) pair
  float d0 = rec.x, d1 = rec.z, d2 = FLT_BIG, d3 = FLT_BIG;
  int i0 = __float_as_int(rec.y), i1 = __float_as_int(rec.w);
  int i2 = 0x7fffffff, i3 = 0x7fffffff;
#pragma unroll
  for (int s2 = 1; s2 < 64; s2 <<= 1) {
    float e0 = __shfl_xor(d0, s2, 64), e1 = __shfl_xor(d1, s2, 64);
    float e2 = __shfl_xor(d2, s2, 64), e3 = __shfl_xor(d3, s2, 64);
    int   j0 = __shfl_xor(i0, s2, 64), j1 = __shfl_xor(i1, s2, 64);
    int   j2 = __shfl_xor(i2, s2, 64), j3 = __shfl_xor(i3, s2, 64);
    top4_insert(e0, j0, d0, i0, d1, i1, d2, i2, d3, i3);
    top4_insert(e1, j1, d0, i0, d1, i1, d2, i2, d3, i3);
    top4_insert(e2, j2, d0, i0, d1, i1, d2, i2, d3, i3);
    top4_insert(e3, j3, d0, i0, d1, i1, d2, i2, d3, i3);
  }

  // exact f32 rescore of 4 candidates (deterministic order)
  const float4* xr = (const float4*)(x + (size_t)row * D);
  const float4* c0 = (const float4*)(cb + (size_t)i0 * D);
  const float4* c1 = (const float4*)(cb + (size_t)i1 * D);
  const float4* c2 = (const float4*)(cb + (size_t)i2 * D);
  const float4* c3 = (const float4*)(cb + (size_t)i3 * D);
  float xsq = 0.f, t0 = 0.f, t1 = 0.f, t2 = 0.f, t3 = 0.f;
#pragma unroll
  for (int u = 0; u < 2; ++u) {
    float4 xv = xr[l + 64 * u];
    float4 a = c0[l + 64 * u], b = c1[l + 64 * u];
    float4 c = c2[l + 64 * u], e = c3[l + 64 * u];
    xsq += xv.x * xv.x + xv.y * xv.y + xv.z * xv.z + xv.w * xv.w;
    t0 += xv.x * a.x + xv.y * a.y + xv.z * a.z + xv.w * a.w;
    t1 += xv.x * b.x + xv.y * b.y + xv.z * b.z + xv.w * b.w;
    t2 += xv.x * c.x + xv.y * c.y + xv.z * c.z + xv.w * c.w;
    t3 += xv.x * e.x + xv.y * e.y + xv.z * e.z + xv.w * e.w;
  }
#pragma unroll
  for (int s2 = 1; s2 < 64; s2 <<= 1) {
    xsq += __shfl_xor(xsq, s2, 64);
    t0 += __shfl_xor(t0, s2, 64); t1 += __shfl_xor(t1, s2, 64);
    t2 += __shfl_xor(t2, s2, 64); t3 += __shfl_xor(t3, s2, 64);
  }
  float D0 = xsq - 2.0f * t0 + e_sq[i0];
  float D1 = xsq - 2.0f * t1 + e_sq[i1];
  float D2 = xsq - 2.0f * t2 + e_sq[i2];
  float D3 = xsq - 2.0f * t3 + e_sq[i3];
  float bdist = D0; int best = i0;
  if (D1 < bdist || (D1 == bdist && i1 < best)) { bdist = D1; best = i1; }
  if (D2 < bdist || (D2 == bdist && i2 < best)) { bdist = D2; best = i2; }
  if (D3 < bdist || (D3 == bdist && i3 < best)) { bdist = D3; best = i3; }

  const float4* vsrc = (const float4*)(values + (size_t)best * D);
  float4* dst = (float4*)(out + (size_t)row * D);
  dst[l] = vsrc[l];
  dst[l + 64] = vsrc[l + 64];
}

// ======================= fallback (R1 f32-VALU path) =========================
#define BM 32
#define BN 64
#define BD 32
#define LDP (BD + 4)

__global__ __launch_bounds__(256)
void sumsq_kernel(const float* __restrict__ x, const float* __restrict__ cb,
                  float* __restrict__ x_sq, float* __restrict__ e_sq) {
  int gwave = (blockIdx.x * 256 + threadIdx.x) >> 6;
  int lane  = threadIdx.x & 63;
  const float* src; float* dst;
  if (gwave < M) { src = x + (size_t)gwave * D; dst = x_sq + gwave; }
  else           { src = cb + (size_t)(gwave - M) * D; dst = e_sq + (gwave - M); }
  const float4* src4 = (const float4*)src;
  float s = 0.f;
#pragma unroll
  for (int i = 0; i < 2; ++i) {
    float4 v = src4[lane + i * 64];
    s += v.x * v.x + v.y * v.y + v.z * v.z + v.w * v.w;
  }
#pragma unroll
  for (int off = 32; off > 0; off >>= 1) s += __shfl_down(s, off, 64);
  if (lane == 0) *dst = s;
}

__global__ __launch_bounds__(256, 2)
void vq_argmin_gather(const float* __restrict__ x, const float* __restrict__ cb,
                      const float* __restrict__ values,
                      const float* __restrict__ x_sq, const float* __restrict__ e_sq,
                      float* __restrict__ out) {
  __shared__ float x_lds[BM][LDP];
  __shared__ float e_lds[BN][LDP];
  __shared__ float red_d[BM][17];
  __shared__ int   red_i[BM][17];
  __shared__ int   bestk[BM];
  const int tid = threadIdx.x;
  const int tx = tid & 15, ty = tid >> 4;
  const int r0 = blockIdx.x * BM, row0 = ty * 2;
  float xsqr[2] = {x_sq[r0 + row0], x_sq[r0 + row0 + 1]};
  float bd[2] = {FLT_BIG, FLT_BIG};
  int bi[2] = {0, 0};
  for (int kc = 0; kc < NCODE; kc += BN) {
    float acc[2][4] = {{0.f,0.f,0.f,0.f},{0.f,0.f,0.f,0.f}};
    for (int ds_ = 0; ds_ < D; ds_ += BD) {
      __syncthreads();
      { int row = tid >> 3, c4 = tid & 7;
        *(float4*)&x_lds[row][c4*4] = *(const float4*)(x + (size_t)(r0+row)*D + ds_ + c4*4); }
#pragma unroll
      for (int u = 0; u < 2; ++u) {
        int g2 = tid + u * 256, er = g2 >> 3, ec4 = g2 & 7;
        *(float4*)&e_lds[er][ec4*4] = *(const float4*)(cb + (size_t)(kc+er)*D + ds_ + ec4*4);
      }
      __syncthreads();
#pragma unroll
      for (int dg = 0; dg < BD; dg += 4) {
        float4 xv0 = *(const float4*)&x_lds[row0][dg];
        float4 xv1 = *(const float4*)&x_lds[row0+1][dg];
        float4 ev[4];
#pragma unroll
        for (int j = 0; j < 4; ++j) ev[j] = *(const float4*)&e_lds[tx + 16*j][dg];
#pragma unroll
        for (int j = 0; j < 4; ++j) {
          acc[0][j] += xv0.x*ev[j].x; acc[0][j] += xv0.y*ev[j].y;
          acc[0][j] += xv0.z*ev[j].z; acc[0][j] += xv0.w*ev[j].w;
          acc[1][j] += xv1.x*ev[j].x; acc[1][j] += xv1.y*ev[j].y;
          acc[1][j] += xv1.z*ev[j].z; acc[1][j] += xv1.w*ev[j].w;
        }
      }
    }
#pragma unroll
    for (int j = 0; j < 4; ++j) {
      int code = kc + tx + 16*j;
      float es2 = e_sq[code];
#pragma unroll
      for (int i = 0; i < 2; ++i) {
        float dist = xsqr[i] - 2.0f*acc[i][j] + es2;
        if (dist < bd[i] || (dist == bd[i] && code < bi[i])) { bd[i] = dist; bi[i] = code; }
      }
    }
  }
  __syncthreads();
#pragma unroll
  for (int i = 0; i < 2; ++i) { red_d[row0+i][tx] = bd[i]; red_i[row0+i][tx] = bi[i]; }
  __syncthreads();
  if (tid < BM) {
    float b = red_d[tid][0]; int idx = red_i[tid][0];
#pragma unroll
    for (int t = 1; t < 16; ++t) {
      float dd = red_d[tid][t]; int ii = red_i[tid][t];
      if (dd < b || (dd == b && ii < idx)) { b = dd; idx = ii; }
    }
    bestk[tid] = idx;
  }
  __syncthreads();
#pragma unroll
  for (int u = 0; u < 16; ++u) {
    int f = u * 256 + tid, row = f >> 7, q = f & 127;
    *(float4*)(out + (size_t)(r0+row)*D + q*4) =
        *(const float4*)(values + (size_t)bestk[row]*D + q*4);
  }
}

// ============================================================================
extern "C" void kernel_launch(void* const* d_in, const int* in_sizes, int n_in,
                              void* d_out, int out_size, void* d_ws, size_t ws_size,
                              hipStream_t stream) {
  const float* x      = (const float*)d_in[0];
  const float* cb     = (const float*)d_in[1];
  const float* values = (const float*)d_in[2];
  float* out = (float*)d_out;

  const size_t A_BYTES = (size_t)M * KH * 2;        // 16 MB
  const size_t B_BYTES = (size_t)NCODE * KH * 2;    // 8 MB
  const size_t C_BYTES = (size_t)M * NB * 16;       // 16 MB
  const size_t E_BYTES = (size_t)NCODE * 4;         // 32 KB
  const size_t NEED = A_BYTES + B_BYTES + C_BYTES + E_BYTES;

  if (ws_size >= NEED) {
    char* base = (char*)d_ws;
    __hip_bfloat16* Ahi = (__hip_bfloat16*)base;
    __hip_bfloat16* Bhi = (__hip_bfloat16*)(base + A_BYTES);
    float4* cand = (float4*)(base + A_BYTES + B_BYTES);
    float* e_sq  = (float*)(base + A_BYTES + B_BYTES + C_BYTES);

    prep_hi<<<2048, 256, 0, stream>>>(x, Ahi, M);
    prep_hi<<<1024, 256, 0, stream>>>(cb, Bhi, NCODE);
    rowsumsq<<<NCODE / 4, 256, 0, stream>>>(cb, e_sq, NCODE);
    vq_gemm_top2<<<(M / 128) * NB, 256, 0, stream>>>(Ahi, Bhi, e_sq, cand);
    vq_merge_rescore<<<M / 4, 256, 0, stream>>>(x, cb, values, e_sq, cand, out);
  } else {
    float* x_sq = (float*)d_ws;
    float* e_sq = x_sq + M;
    sumsq_kernel<<<(M + NCODE) / 4, 256, 0, stream>>>(x, cb, x_sq, e_sq);
    vq_argmin_gather<<<M / BM, 256, 0, stream>>>(x, cb, values, x_sq, e_sq, out);
  }
}

// Round 4
// 1227.703 us; speedup vs baseline: 3.3252x; 1.0705x over previous
//
#include <hip/hip_runtime.h>
#include <hip/hip_bf16.h>

// VectorQuantize: argmin_k ||x - e_k||^2 then gather values[k].
// R4: hi-bf16 candidate GEMM (K=512), T3-minimum 2-phase double-buffer
// (STAGE(next) -> ds_read(cur) -> MFMA -> __syncthreads; one barrier/step,
// NO inline asm), L2-aware XCD block ordering, per-tile top-2 -> global
// top-4 -> exact f32 rescore (np tie semantics) -> gather values[best].

#define D      512
#define M      16384
#define NCODE  8192
#define KH     512         // hi-only packed K
#define NB     64          // NCODE / 128 tiles per row
#define NSTEP  16          // KH / 32

typedef float f32x4  __attribute__((ext_vector_type(4)));
typedef short bf16x8 __attribute__((ext_vector_type(8)));

#define FLT_BIG 3.402823466e38f

__device__ __forceinline__ void gload16(const __hip_bfloat16* g, __hip_bfloat16* l) {
  __builtin_amdgcn_global_load_lds(
      (const __attribute__((address_space(1))) void*)g,
      (__attribute__((address_space(3))) void*)l, 16, 0, 0);
}

__device__ __forceinline__ void top2_insert(float d, int i,
                                            float& d1, int& i1, float& d2, int& i2) {
  bool lt1 = (d < d1) || (d == d1 && i < i1);
  bool lt2 = (d < d2) || (d == d2 && i < i2);
  if (lt1) { d2 = d1; i2 = i1; d1 = d; i1 = i; }
  else if (lt2) { d2 = d; i2 = i; }
}

__device__ __forceinline__ void top4_insert(float nd, int ni,
    float& d0, int& i0, float& d1, int& i1,
    float& d2, int& i2, float& d3, int& i3) {
  bool l0 = (nd < d0) || (nd == d0 && ni < i0);
  bool l1 = (nd < d1) || (nd == d1 && ni < i1);
  bool l2 = (nd < d2) || (nd == d2 && ni < i2);
  bool l3 = (nd < d3) || (nd == d3 && ni < i3);
  if (l0)      { d3 = d2; i3 = i2; d2 = d1; i2 = i1; d1 = d0; i1 = i0; d0 = nd; i0 = ni; }
  else if (l1) { d3 = d2; i3 = i2; d2 = d1; i2 = i1; d1 = nd; i1 = ni; }
  else if (l2) { d3 = d2; i3 = i2; d2 = nd; i2 = ni; }
  else if (l3) { d3 = nd; i3 = ni; }
}

// ---- 1. f32 -> hi-bf16 pack -------------------------------------------------
__global__ __launch_bounds__(256)
void prep_hi(const float* __restrict__ src, __hip_bfloat16* __restrict__ pack,
             int nrows) {
  int total = nrows * (D / 4);
  for (int idx = blockIdx.x * 256 + threadIdx.x; idx < total; idx += gridDim.x * 256) {
    float4 v = ((const float4*)src)[idx];
    float vv[4] = {v.x, v.y, v.z, v.w};
    ushort4 uh;
    unsigned short* ph = (unsigned short*)&uh;
#pragma unroll
    for (int j = 0; j < 4; ++j) {
      __hip_bfloat16 h = __float2bfloat16(vv[j]);   // round-to-nearest-even
      ph[j] = *(unsigned short*)&h;
    }
    ((ushort4*)pack)[idx] = uh;
  }
}

// ---- 2. exact f32 row sum-of-squares (codebook) -----------------------------
__global__ __launch_bounds__(256)
void rowsumsq(const float* __restrict__ src, float* __restrict__ dst, int nrows) {
  int gw = (blockIdx.x * 256 + threadIdx.x) >> 6;
  if (gw >= nrows) return;
  int lane = threadIdx.x & 63;
  const float4* s4 = (const float4*)(src + (size_t)gw * D);
  float s = 0.f;
#pragma unroll
  for (int i = 0; i < 2; ++i) {
    float4 v = s4[lane + i * 64];
    s += v.x * v.x + v.y * v.y + v.z * v.z + v.w * v.w;
  }
#pragma unroll
  for (int off = 32; off > 0; off >>= 1) s += __shfl_down(s, off, 64);
  if (lane == 0) dst[gw] = s;
}

// ---- 3. hi-bf16 MFMA GEMM, 2-phase dbuf, fused per-tile top-2 ---------------
__global__ __launch_bounds__(256, 3)
void vq_gemm_top2(const __hip_bfloat16* __restrict__ Ahi,
                  const __hip_bfloat16* __restrict__ Bhi,
                  const float* __restrict__ e_sq,
                  float4* __restrict__ cand) {
  __shared__ __hip_bfloat16 As[2][128 * 32];   // 2 x 8 KB
  __shared__ __hip_bfloat16 Bs[2][128 * 32];   // 2 x 8 KB
  __shared__ float4 red[128][2];               // 4 KB

  const int tid = threadIdx.x;
  const int w = tid >> 6, l = tid & 63;
  const int wr = w >> 1, wc = w & 1;
  const int lr = l & 15, lh = l >> 4;

  // L2-aware XCD ordering (validated by R3 FETCH ~= minimal):
  // per XCD, 8-nt groups, mt sweep within group; WS ~3 MB < 4 MB L2.
  const int bid = blockIdx.x;
  const int xcd = bid & 7, idx = bid >> 3;     // 1024 blocks per XCD
  const int g = idx >> 7;                      // 8 nt-groups of 8
  const int rem = idx & 127;
  const int mtl = rem >> 3, ntl = rem & 7;
  const int mt = xcd * 16 + mtl;               // 128 m-tiles
  const int nt = g * 8 + ntl;                  // 64 n-tiles
  const int row0 = mt * 128, col0 = nt * 128;

  f32x4 acc[4][4] = {};

  // staging geometry: granule f in [0,512): row = f&127, k16 = f>>7
  const int f0 = tid, f1 = tid + 256;
  const int ra0 = f0 & 127, ka0 = f0 >> 7;
  const int ra1 = f1 & 127, ka1 = f1 >> 7;

#define STAGE(buf, t)                                                            \
  do {                                                                           \
    const int kk = (t) * 32;                                                     \
    gload16(Ahi + (size_t)(row0 + ra0) * KH + kk + ka0 * 8, As[(buf)] + f0 * 8); \
    gload16(Ahi + (size_t)(row0 + ra1) * KH + kk + ka1 * 8, As[(buf)] + f1 * 8); \
    gload16(Bhi + (size_t)(col0 + ra0) * KH + kk + ka0 * 8, Bs[(buf)] + f0 * 8); \
    gload16(Bhi + (size_t)(col0 + ra1) * KH + kk + ka1 * 8, Bs[(buf)] + f1 * 8); \
  } while (0)

#define COMPUTE(buf)                                                             \
  do {                                                                           \
    const bf16x8* Ag = (const bf16x8*)As[(buf)];                                 \
    const bf16x8* Bg = (const bf16x8*)Bs[(buf)];                                 \
    bf16x8 a[4], b[4];                                                           \
    _Pragma("unroll")                                                            \
    for (int m = 0; m < 4; ++m) a[m] = Ag[lh * 128 + wr * 64 + m * 16 + lr];     \
    _Pragma("unroll")                                                            \
    for (int n = 0; n < 4; ++n) b[n] = Bg[lh * 128 + wc * 64 + n * 16 + lr];     \
    _Pragma("unroll")                                                            \
    for (int m = 0; m < 4; ++m)                                                  \
      _Pragma("unroll")                                                          \
      for (int n = 0; n < 4; ++n)                                                \
        acc[m][n] = __builtin_amdgcn_mfma_f32_16x16x32_bf16(a[m], b[n], acc[m][n], 0, 0, 0); \
  } while (0)

  STAGE(0, 0);
  __syncthreads();                 // stage-0 landed

#pragma unroll 1
  for (int t = 0; t < NSTEP - 1; ++t) {
    const int cur = t & 1;
    STAGE(cur ^ 1, t + 1);         // prefetch issued BEFORE compute phase
    COMPUTE(cur);
    __syncthreads();               // one barrier/step: drains prefetch (latency
                                   // already hidden under COMPUTE) + read-retire
  }
  COMPUTE((NSTEP - 1) & 1);        // final step, no prefetch

#undef STAGE
#undef COMPUTE

  // ---- epilogue: per-row top-2 of approx score within this 128x128 tile ----
  float es[4];
#pragma unroll
  for (int n = 0; n < 4; ++n) es[n] = e_sq[col0 + wc * 64 + n * 16 + lr];

#pragma unroll
  for (int m = 0; m < 4; ++m) {
#pragma unroll
    for (int q = 0; q < 4; ++q) {
      float d1 = FLT_BIG, d2 = FLT_BIG;
      int   i1 = 0x7fffffff, i2 = 0x7fffffff;
#pragma unroll
      for (int n = 0; n < 4; ++n) {
        int cl = wc * 64 + n * 16 + lr;
        float sc = es[n] - 2.0f * acc[m][n][q];
        top2_insert(sc, col0 + cl, d1, i1, d2, i2);
      }
#pragma unroll
      for (int s2 = 1; s2 < 16; s2 <<= 1) {
        float od1 = __shfl_xor(d1, s2, 64); int oi1 = __shfl_xor(i1, s2, 64);
        float od2 = __shfl_xor(d2, s2, 64); int oi2 = __shfl_xor(i2, s2, 64);
        top2_insert(od1, oi1, d1, i1, d2, i2);
        top2_insert(od2, oi2, d1, i1, d2, i2);
      }
      if (lr == 0)
        red[wr * 64 + m * 16 + lh * 4 + q][wc] =
            make_float4(d1, __int_as_float(i1), d2, __int_as_float(i2));
    }
  }
  __syncthreads();
  if (tid < 128) {
    float4 r0 = red[tid][0], r1 = red[tid][1];
    float d1 = r0.x; int i1 = __float_as_int(r0.y);
    float d2 = r0.z; int i2 = __float_as_int(r0.w);
    top2_insert(r1.x, __float_as_int(r1.y), d1, i1, d2, i2);
    top2_insert(r1.z, __float_as_int(r1.w), d1, i1, d2, i2);
    cand[(size_t)(row0 + tid) * NB + nt] =
        make_float4(d1, __int_as_float(i1), d2, __int_as_float(i2));
  }
}

// ---- 4. global top-4, exact f32 rescore, gather -----------------------------
__global__ __launch_bounds__(256)
void vq_merge_rescore(const float* __restrict__ x, const float* __restrict__ cb,
                      const float* __restrict__ values, const float* __restrict__ e_sq,
                      const float4* __restrict__ cand, float* __restrict__ out) {
  int row = blockIdx.x * 4 + (threadIdx.x >> 6);
  int l = threadIdx.x & 63;

  float4 rec = cand[(size_t)row * NB + l];      // lane l: tile l's (d1<=d2) pair
  float d0 = rec.x, d1 = rec.z, d2 = FLT_BIG, d3 = FLT_BIG;
  int i0 = __float_as_int(rec.y), i1 = __float_as_int(rec.w);
  int i2 = 0x7fffffff, i3 = 0x7fffffff;
#pragma unroll
  for (int s2 = 1; s2 < 64; s2 <<= 1) {
    float e0 = __shfl_xor(d0, s2, 64), e1 = __shfl_xor(d1, s2, 64);
    float e2 = __shfl_xor(d2, s2, 64), e3 = __shfl_xor(d3, s2, 64);
    int   j0 = __shfl_xor(i0, s2, 64), j1 = __shfl_xor(i1, s2, 64);
    int   j2 = __shfl_xor(i2, s2, 64), j3 = __shfl_xor(i3, s2, 64);
    top4_insert(e0, j0, d0, i0, d1, i1, d2, i2, d3, i3);
    top4_insert(e1, j1, d0, i0, d1, i1, d2, i2, d3, i3);
    top4_insert(e2, j2, d0, i0, d1, i1, d2, i2, d3, i3);
    top4_insert(e3, j3, d0, i0, d1, i1, d2, i2, d3, i3);
  }

  // exact f32 rescore of 4 candidates (deterministic order)
  const float4* xr = (const float4*)(x + (size_t)row * D);
  const float4* c0 = (const float4*)(cb + (size_t)i0 * D);
  const float4* c1 = (const float4*)(cb + (size_t)i1 * D);
  const float4* c2 = (const float4*)(cb + (size_t)i2 * D);
  const float4* c3 = (const float4*)(cb + (size_t)i3 * D);
  float xsq = 0.f, t0 = 0.f, t1 = 0.f, t2 = 0.f, t3 = 0.f;
#pragma unroll
  for (int u = 0; u < 2; ++u) {
    float4 xv = xr[l + 64 * u];
    float4 a = c0[l + 64 * u], b = c1[l + 64 * u];
    float4 c = c2[l + 64 * u], e = c3[l + 64 * u];
    xsq += xv.x * xv.x + xv.y * xv.y + xv.z * xv.z + xv.w * xv.w;
    t0 += xv.x * a.x + xv.y * a.y + xv.z * a.z + xv.w * a.w;
    t1 += xv.x * b.x + xv.y * b.y + xv.z * b.z + xv.w * b.w;
    t2 += xv.x * c.x + xv.y * c.y + xv.z * c.z + xv.w * c.w;
    t3 += xv.x * e.x + xv.y * e.y + xv.z * e.z + xv.w * e.w;
  }
#pragma unroll
  for (int s2 = 1; s2 < 64; s2 <<= 1) {
    xsq += __shfl_xor(xsq, s2, 64);
    t0 += __shfl_xor(t0, s2, 64); t1 += __shfl_xor(t1, s2, 64);
    t2 += __shfl_xor(t2, s2, 64); t3 += __shfl_xor(t3, s2, 64);
  }
  float D0 = xsq - 2.0f * t0 + e_sq[i0];
  float D1 = xsq - 2.0f * t1 + e_sq[i1];
  float D2 = xsq - 2.0f * t2 + e_sq[i2];
  float D3 = xsq - 2.0f * t3 + e_sq[i3];
  float bdist = D0; int best = i0;
  if (D1 < bdist || (D1 == bdist && i1 < best)) { bdist = D1; best = i1; }
  if (D2 < bdist || (D2 == bdist && i2 < best)) { bdist = D2; best = i2; }
  if (D3 < bdist || (D3 == bdist && i3 < best)) { bdist = D3; best = i3; }

  const float4* vsrc = (const float4*)(values + (size_t)best * D);
  float4* dst = (float4*)(out + (size_t)row * D);
  dst[l] = vsrc[l];
  dst[l + 64] = vsrc[l + 64];
}

// ======================= fallback (R1 f32-VALU path) =========================
#define BM 32
#define BN 64
#define BD 32
#define LDP (BD + 4)

__global__ __launch_bounds__(256)
void sumsq_kernel(const float* __restrict__ x, const float* __restrict__ cb,
                  float* __restrict__ x_sq, float* __restrict__ e_sq) {
  int gwave = (blockIdx.x * 256 + threadIdx.x) >> 6;
  int lane  = threadIdx.x & 63;
  const float* src; float* dst;
  if (gwave < M) { src = x + (size_t)gwave * D; dst = x_sq + gwave; }
  else           { src = cb + (size_t)(gwave - M) * D; dst = e_sq + (gwave - M); }
  const float4* src4 = (const float4*)src;
  float s = 0.f;
#pragma unroll
  for (int i = 0; i < 2; ++i) {
    float4 v = src4[lane + i * 64];
    s += v.x * v.x + v.y * v.y + v.z * v.z + v.w * v.w;
  }
#pragma unroll
  for (int off = 32; off > 0; off >>= 1) s += __shfl_down(s, off, 64);
  if (lane == 0) *dst = s;
}

__global__ __launch_bounds__(256, 2)
void vq_argmin_gather(const float* __restrict__ x, const float* __restrict__ cb,
                      const float* __restrict__ values,
                      const float* __restrict__ x_sq, const float* __restrict__ e_sq,
                      float* __restrict__ out) {
  __shared__ float x_lds[BM][LDP];
  __shared__ float e_lds[BN][LDP];
  __shared__ float red_d[BM][17];
  __shared__ int   red_i[BM][17];
  __shared__ int   bestk[BM];
  const int tid = threadIdx.x;
  const int tx = tid & 15, ty = tid >> 4;
  const int r0 = blockIdx.x * BM, row0 = ty * 2;
  float xsqr[2] = {x_sq[r0 + row0], x_sq[r0 + row0 + 1]};
  float bd[2] = {FLT_BIG, FLT_BIG};
  int bi[2] = {0, 0};
  for (int kc = 0; kc < NCODE; kc += BN) {
    float acc[2][4] = {{0.f,0.f,0.f,0.f},{0.f,0.f,0.f,0.f}};
    for (int ds_ = 0; ds_ < D; ds_ += BD) {
      __syncthreads();
      { int row = tid >> 3, c4 = tid & 7;
        *(float4*)&x_lds[row][c4*4] = *(const float4*)(x + (size_t)(r0+row)*D + ds_ + c4*4); }
#pragma unroll
      for (int u = 0; u < 2; ++u) {
        int g2 = tid + u * 256, er = g2 >> 3, ec4 = g2 & 7;
        *(float4*)&e_lds[er][ec4*4] = *(const float4*)(cb + (size_t)(kc+er)*D + ds_ + ec4*4);
      }
      __syncthreads();
#pragma unroll
      for (int dg = 0; dg < BD; dg += 4) {
        float4 xv0 = *(const float4*)&x_lds[row0][dg];
        float4 xv1 = *(const float4*)&x_lds[row0+1][dg];
        float4 ev[4];
#pragma unroll
        for (int j = 0; j < 4; ++j) ev[j] = *(const float4*)&e_lds[tx + 16*j][dg];
#pragma unroll
        for (int j = 0; j < 4; ++j) {
          acc[0][j] += xv0.x*ev[j].x; acc[0][j] += xv0.y*ev[j].y;
          acc[0][j] += xv0.z*ev[j].z; acc[0][j] += xv0.w*ev[j].w;
          acc[1][j] += xv1.x*ev[j].x; acc[1][j] += xv1.y*ev[j].y;
          acc[1][j] += xv1.z*ev[j].z; acc[1][j] += xv1.w*ev[j].w;
        }
      }
    }
#pragma unroll
    for (int j = 0; j < 4; ++j) {
      int code = kc + tx + 16*j;
      float es2 = e_sq[code];
#pragma unroll
      for (int i = 0; i < 2; ++i) {
        float dist = xsqr[i] - 2.0f*acc[i][j] + es2;
        if (dist < bd[i] || (dist == bd[i] && code < bi[i])) { bd[i] = dist; bi[i] = code; }
      }
    }
  }
  __syncthreads();
#pragma unroll
  for (int i = 0; i < 2; ++i) { red_d[row0+i][tx] = bd[i]; red_i[row0+i][tx] = bi[i]; }
  __syncthreads();
  if (tid < BM) {
    float b = red_d[tid][0]; int idx = red_i[tid][0];
#pragma unroll
    for (int t = 1; t < 16; ++t) {
      float dd = red_d[tid][t]; int ii = red_i[tid][t];
      if (dd < b || (dd == b && ii < idx)) { b = dd; idx = ii; }
    }
    bestk[tid] = idx;
  }
  __syncthreads();
#pragma unroll
  for (int u = 0; u < 16; ++u) {
    int f = u * 256 + tid, row = f >> 7, q = f & 127;
    *(float4*)(out + (size_t)(r0+row)*D + q*4) =
        *(const float4*)(values + (size_t)bestk[row]*D + q*4);
  }
}

// ============================================================================
extern "C" void kernel_launch(void* const* d_in, const int* in_sizes, int n_in,
                              void* d_out, int out_size, void* d_ws, size_t ws_size,
                              hipStream_t stream) {
  const float* x      = (const float*)d_in[0];
  const float* cb     = (const float*)d_in[1];
  const float* values = (const float*)d_in[2];
  float* out = (float*)d_out;

  const size_t A_BYTES = (size_t)M * KH * 2;        // 16 MB
  const size_t B_BYTES = (size_t)NCODE * KH * 2;    // 8 MB
  const size_t C_BYTES = (size_t)M * NB * 16;       // 16 MB
  const size_t E_BYTES = (size_t)NCODE * 4;         // 32 KB
  const size_t NEED = A_BYTES + B_BYTES + C_BYTES + E_BYTES;

  if (ws_size >= NEED) {
    char* base = (char*)d_ws;
    __hip_bfloat16* Ahi = (__hip_bfloat16*)base;
    __hip_bfloat16* Bhi = (__hip_bfloat16*)(base + A_BYTES);
    float4* cand = (float4*)(base + A_BYTES + B_BYTES);
    float* e_sq  = (float*)(base + A_BYTES + B_BYTES + C_BYTES);

    prep_hi<<<2048, 256, 0, stream>>>(x, Ahi, M);
    prep_hi<<<1024, 256, 0, stream>>>(cb, Bhi, NCODE);
    rowsumsq<<<NCODE / 4, 256, 0, stream>>>(cb, e_sq, NCODE);
    vq_gemm_top2<<<(M / 128) * NB, 256, 0, stream>>>(Ahi, Bhi, e_sq, cand);
    vq_merge_rescore<<<M / 4, 256, 0, stream>>>(x, cb, values, e_sq, cand, out);
  } else {
    float* x_sq = (float*)d_ws;
    float* e_sq = x_sq + M;
    sumsq_kernel<<<(M + NCODE) / 4, 256, 0, stream>>>(x, cb, x_sq, e_sq);
    vq_argmin_gather<<<M / BM, 256, 0, stream>>>(x, cb, values, x_sq, e_sq, out);
  }
}

// Round 5
// 1115.964 us; speedup vs baseline: 3.6581x; 1.1001x over previous
//
#include <hip/hip_runtime.h>
#include <hip/hip_bf16.h>

// VectorQuantize: argmin_k ||x - e_k||^2 then gather values[k].
// R5: hi-bf16 candidate GEMM (K=512) with TILE-TRANSPOSED operand packs so
// global->LDS staging is lane-linear (1 KB contiguous per wave instruction);
// 2-phase double-buffer (one barrier/step), L2-aware XCD ordering, per-tile
// top-2 -> global top-4 -> exact f32 rescore (np tie semantics) -> gather.
//
// Pack layout: P[tile][k16][row][8] bf16, tile = 128 rows, k16 = 64 granules
// of 8 elems (K=512). A: 128 tiles (16 MB). B: 64 tiles (8 MB).
// GEMM K-step t stages granules k16 = 4t..4t+3: a contiguous 8 KB slab whose
// granule index f = k16l*128 + row EQUALS the LDS granule index -> source
// address = base + (t*512 + f)*8 elems, perfectly coalesced.

#define D      512
#define M      16384
#define NCODE  8192
#define KH     512         // hi-only packed K
#define NB     64          // NCODE / 128 tiles per row
#define NSTEP  16          // KH / 32

typedef float f32x4  __attribute__((ext_vector_type(4)));
typedef short bf16x8 __attribute__((ext_vector_type(8)));

#define FLT_BIG 3.402823466e38f

__device__ __forceinline__ void gload16(const __hip_bfloat16* g, __hip_bfloat16* l) {
  __builtin_amdgcn_global_load_lds(
      (const __attribute__((address_space(1))) void*)g,
      (__attribute__((address_space(3))) void*)l, 16, 0, 0);
}

__device__ __forceinline__ void top2_insert(float d, int i,
                                            float& d1, int& i1, float& d2, int& i2) {
  bool lt1 = (d < d1) || (d == d1 && i < i1);
  bool lt2 = (d < d2) || (d == d2 && i < i2);
  if (lt1) { d2 = d1; i2 = i1; d1 = d; i1 = i; }
  else if (lt2) { d2 = d; i2 = i; }
}

__device__ __forceinline__ void top4_insert(float nd, int ni,
    float& d0, int& i0, float& d1, int& i1,
    float& d2, int& i2, float& d3, int& i3) {
  bool l0 = (nd < d0) || (nd == d0 && ni < i0);
  bool l1 = (nd < d1) || (nd == d1 && ni < i1);
  bool l2 = (nd < d2) || (nd == d2 && ni < i2);
  bool l3 = (nd < d3) || (nd == d3 && ni < i3);
  if (l0)      { d3 = d2; i3 = i2; d2 = d1; i2 = i1; d1 = d0; i1 = i0; d0 = nd; i0 = ni; }
  else if (l1) { d3 = d2; i3 = i2; d2 = d1; i2 = i1; d1 = nd; i1 = ni; }
  else if (l2) { d3 = d2; i3 = i2; d2 = nd; i2 = ni; }
  else if (l3) { d3 = nd; i3 = ni; }
}

// ---- 1. f32 -> hi-bf16 tile-transposed pack ---------------------------------
// One block per 128-row tile. 4 column-chunks of 128 f32 (16 k16-granules).
// Reads coalesced (lanes sweep k16 within a row), transposes through LDS,
// writes granule-major (k16*128+row) -> lane-linear 16B stores.
__global__ __launch_bounds__(256)
void prep_tile(const float* __restrict__ src, __hip_bfloat16* __restrict__ dst) {
  __shared__ __hip_bfloat16 tile[128][136];   // 34 KB; 272B row stride, 16B-aligned
  const int tid = threadIdx.x;
  const float* srow = src + (size_t)blockIdx.x * 128 * D;
  __hip_bfloat16* dbase = dst + (size_t)blockIdx.x * 64 * 128 * 8;

#pragma unroll 1
  for (int c = 0; c < 4; ++c) {
    __syncthreads();   // LDS reuse across chunks
#pragma unroll
    for (int j = 0; j < 8; ++j) {
      int f = tid + j * 256;               // 2048 granules: k16l = f&15, row = f>>4
      int row = f >> 4, k16l = f & 15;
      const float4* p = (const float4*)(srow + (size_t)row * D + c * 128 + k16l * 8);
      float4 v0 = p[0], v1 = p[1];
      float vv[8] = {v0.x, v0.y, v0.z, v0.w, v1.x, v1.y, v1.z, v1.w};
      union { bf16x8 v; unsigned short u[8]; } pk;
#pragma unroll
      for (int e = 0; e < 8; ++e) {
        __hip_bfloat16 h = __float2bfloat16(vv[e]);   // RNE
        pk.u[e] = *(unsigned short*)&h;
      }
      *(bf16x8*)&tile[row][k16l * 8] = pk.v;
    }
    __syncthreads();
#pragma unroll
    for (int j = 0; j < 8; ++j) {
      int g = tid + j * 256;               // output granule: row = g&127, k16l = g>>7
      int row = g & 127, k16l = g >> 7;
      bf16x8 v = *(const bf16x8*)&tile[row][k16l * 8];
      *(bf16x8*)(dbase + ((size_t)(c * 16 + k16l) * 128 + row) * 8) = v;
    }
  }
}

// ---- 2. exact f32 row sum-of-squares (codebook) -----------------------------
__global__ __launch_bounds__(256)
void rowsumsq(const float* __restrict__ src, float* __restrict__ dst, int nrows) {
  int gw = (blockIdx.x * 256 + threadIdx.x) >> 6;
  if (gw >= nrows) return;
  int lane = threadIdx.x & 63;
  const float4* s4 = (const float4*)(src + (size_t)gw * D);
  float s = 0.f;
#pragma unroll
  for (int i = 0; i < 2; ++i) {
    float4 v = s4[lane + i * 64];
    s += v.x * v.x + v.y * v.y + v.z * v.z + v.w * v.w;
  }
#pragma unroll
  for (int off = 32; off > 0; off >>= 1) s += __shfl_down(s, off, 64);
  if (lane == 0) dst[gw] = s;
}

// ---- 3. hi-bf16 MFMA GEMM, 2-phase dbuf, coalesced staging, fused top-2 -----
__global__ __launch_bounds__(256, 3)
void vq_gemm_top2(const __hip_bfloat16* __restrict__ Apack,
                  const __hip_bfloat16* __restrict__ Bpack,
                  const float* __restrict__ e_sq,
                  float4* __restrict__ cand) {
  __shared__ __hip_bfloat16 As[2][128 * 32];   // 2 x 8 KB
  __shared__ __hip_bfloat16 Bs[2][128 * 32];   // 2 x 8 KB
  __shared__ float4 red[128][2];               // 4 KB

  const int tid = threadIdx.x;
  const int w = tid >> 6, l = tid & 63;
  const int wr = w >> 1, wc = w & 1;
  const int lr = l & 15, lh = l >> 4;

  // L2-aware XCD ordering (validated: FETCH ~= minimal since R3).
  const int bid = blockIdx.x;
  const int xcd = bid & 7, idx = bid >> 3;     // 1024 blocks per XCD
  const int g = idx >> 7;                      // 8 nt-groups of 8
  const int rem = idx & 127;
  const int mtl = rem >> 3, ntl = rem & 7;
  const int mt = xcd * 16 + mtl;               // 128 m-tiles
  const int nt = g * 8 + ntl;                  // 64 n-tiles
  const int col0 = nt * 128;

  f32x4 acc[4][4] = {};

  // lane-linear staging: granule f = k16l*128 + row, source offset (t*512+f)*8
  const int f0 = tid, f1 = tid + 256;
  const __hip_bfloat16* Abase = Apack + (size_t)mt * 64 * 128 * 8;
  const __hip_bfloat16* Bbase = Bpack + (size_t)nt * 64 * 128 * 8;

#define STAGE(buf, t)                                                      \
  do {                                                                     \
    gload16(Abase + ((size_t)(t) * 512 + f0) * 8, As[(buf)] + f0 * 8);     \
    gload16(Abase + ((size_t)(t) * 512 + f1) * 8, As[(buf)] + f1 * 8);     \
    gload16(Bbase + ((size_t)(t) * 512 + f0) * 8, Bs[(buf)] + f0 * 8);     \
    gload16(Bbase + ((size_t)(t) * 512 + f1) * 8, Bs[(buf)] + f1 * 8);     \
  } while (0)

#define COMPUTE(buf)                                                             \
  do {                                                                           \
    const bf16x8* Ag = (const bf16x8*)As[(buf)];                                 \
    const bf16x8* Bg = (const bf16x8*)Bs[(buf)];                                 \
    bf16x8 a[4], b[4];                                                           \
    _Pragma("unroll")                                                            \
    for (int m = 0; m < 4; ++m) a[m] = Ag[lh * 128 + wr * 64 + m * 16 + lr];     \
    _Pragma("unroll")                                                            \
    for (int n = 0; n < 4; ++n) b[n] = Bg[lh * 128 + wc * 64 + n * 16 + lr];     \
    _Pragma("unroll")                                                            \
    for (int m = 0; m < 4; ++m)                                                  \
      _Pragma("unroll")                                                          \
      for (int n = 0; n < 4; ++n)                                                \
        acc[m][n] = __builtin_amdgcn_mfma_f32_16x16x32_bf16(a[m], b[n], acc[m][n], 0, 0, 0); \
  } while (0)

  STAGE(0, 0);
  __syncthreads();                 // stage-0 landed

#pragma unroll 1
  for (int t = 0; t < NSTEP - 1; ++t) {
    const int cur = t & 1;
    STAGE(cur ^ 1, t + 1);         // prefetch issued BEFORE compute phase
    COMPUTE(cur);
    __syncthreads();               // one barrier/step
  }
  COMPUTE((NSTEP - 1) & 1);        // final step, no prefetch

#undef STAGE
#undef COMPUTE

  // ---- epilogue: per-row top-2 of approx score within this 128x128 tile ----
  float es[4];
#pragma unroll
  for (int n = 0; n < 4; ++n) es[n] = e_sq[col0 + wc * 64 + n * 16 + lr];

#pragma unroll
  for (int m = 0; m < 4; ++m) {
#pragma unroll
    for (int q = 0; q < 4; ++q) {
      float d1 = FLT_BIG, d2 = FLT_BIG;
      int   i1 = 0x7fffffff, i2 = 0x7fffffff;
#pragma unroll
      for (int n = 0; n < 4; ++n) {
        int cl = wc * 64 + n * 16 + lr;
        float sc = es[n] - 2.0f * acc[m][n][q];
        top2_insert(sc, col0 + cl, d1, i1, d2, i2);
      }
#pragma unroll
      for (int s2 = 1; s2 < 16; s2 <<= 1) {
        float od1 = __shfl_xor(d1, s2, 64); int oi1 = __shfl_xor(i1, s2, 64);
        float od2 = __shfl_xor(d2, s2, 64); int oi2 = __shfl_xor(i2, s2, 64);
        top2_insert(od1, oi1, d1, i1, d2, i2);
        top2_insert(od2, oi2, d1, i1, d2, i2);
      }
      if (lr == 0)
        red[wr * 64 + m * 16 + lh * 4 + q][wc] =
            make_float4(d1, __int_as_float(i1), d2, __int_as_float(i2));
    }
  }
  __syncthreads();
  if (tid < 128) {
    float4 r0 = red[tid][0], r1 = red[tid][1];
    float d1 = r0.x; int i1 = __float_as_int(r0.y);
    float d2 = r0.z; int i2 = __float_as_int(r0.w);
    top2_insert(r1.x, __float_as_int(r1.y), d1, i1, d2, i2);
    top2_insert(r1.z, __float_as_int(r1.w), d1, i1, d2, i2);
    cand[(size_t)(mt * 128 + tid) * NB + nt] =
        make_float4(d1, __int_as_float(i1), d2, __int_as_float(i2));
  }
}

// ---- 4. global top-4, exact f32 rescore, gather -----------------------------
__global__ __launch_bounds__(256)
void vq_merge_rescore(const float* __restrict__ x, const float* __restrict__ cb,
                      const float* __restrict__ values, const float* __restrict__ e_sq,
                      const float4* __restrict__ cand, float* __restrict__ out) {
  int row = blockIdx.x * 4 + (threadIdx.x >> 6);
  int l = threadIdx.x & 63;

  float4 rec = cand[(size_t)row * NB + l];      // lane l: tile l's (d1<=d2) pair
  float d0 = rec.x, d1 = rec.z, d2 = FLT_BIG, d3 = FLT_BIG;
  int i0 = __float_as_int(rec.y), i1 = __float_as_int(rec.w);
  int i2 = 0x7fffffff, i3 = 0x7fffffff;
#pragma unroll
  for (int s2 = 1; s2 < 64; s2 <<= 1) {
    float e0 = __shfl_xor(d0, s2, 64), e1 = __shfl_xor(d1, s2, 64);
    float e2 = __shfl_xor(d2, s2, 64), e3 = __shfl_xor(d3, s2, 64);
    int   j0 = __shfl_xor(i0, s2, 64), j1 = __shfl_xor(i1, s2, 64);
    int   j2 = __shfl_xor(i2, s2, 64), j3 = __shfl_xor(i3, s2, 64);
    top4_insert(e0, j0, d0, i0, d1, i1, d2, i2, d3, i3);
    top4_insert(e1, j1, d0, i0, d1, i1, d2, i2, d3, i3);
    top4_insert(e2, j2, d0, i0, d1, i1, d2, i2, d3, i3);
    top4_insert(e3, j3, d0, i0, d1, i1, d2, i2, d3, i3);
  }

  // exact f32 rescore of 4 candidates (deterministic order)
  const float4* xr = (const float4*)(x + (size_t)row * D);
  const float4* c0 = (const float4*)(cb + (size_t)i0 * D);
  const float4* c1 = (const float4*)(cb + (size_t)i1 * D);
  const float4* c2 = (const float4*)(cb + (size_t)i2 * D);
  const float4* c3 = (const float4*)(cb + (size_t)i3 * D);
  float xsq = 0.f, t0 = 0.f, t1 = 0.f, t2 = 0.f, t3 = 0.f;
#pragma unroll
  for (int u = 0; u < 2; ++u) {
    float4 xv = xr[l + 64 * u];
    float4 a = c0[l + 64 * u], b = c1[l + 64 * u];
    float4 c = c2[l + 64 * u], e = c3[l + 64 * u];
    xsq += xv.x * xv.x + xv.y * xv.y + xv.z * xv.z + xv.w * xv.w;
    t0 += xv.x * a.x + xv.y * a.y + xv.z * a.z + xv.w * a.w;
    t1 += xv.x * b.x + xv.y * b.y + xv.z * b.z + xv.w * b.w;
    t2 += xv.x * c.x + xv.y * c.y + xv.z * c.z + xv.w * c.w;
    t3 += xv.x * e.x + xv.y * e.y + xv.z * e.z + xv.w * e.w;
  }
#pragma unroll
  for (int s2 = 1; s2 < 64; s2 <<= 1) {
    xsq += __shfl_xor(xsq, s2, 64);
    t0 += __shfl_xor(t0, s2, 64); t1 += __shfl_xor(t1, s2, 64);
    t2 += __shfl_xor(t2, s2, 64); t3 += __shfl_xor(t3, s2, 64);
  }
  float D0 = xsq - 2.0f * t0 + e_sq[i0];
  float D1 = xsq - 2.0f * t1 + e_sq[i1];
  float D2 = xsq - 2.0f * t2 + e_sq[i2];
  float D3 = xsq - 2.0f * t3 + e_sq[i3];
  float bdist = D0; int best = i0;
  if (D1 < bdist || (D1 == bdist && i1 < best)) { bdist = D1; best = i1; }
  if (D2 < bdist || (D2 == bdist && i2 < best)) { bdist = D2; best = i2; }
  if (D3 < bdist || (D3 == bdist && i3 < best)) { bdist = D3; best = i3; }

  const float4* vsrc = (const float4*)(values + (size_t)best * D);
  float4* dst = (float4*)(out + (size_t)row * D);
  dst[l] = vsrc[l];
  dst[l + 64] = vsrc[l + 64];
}

// ======================= fallback (R1 f32-VALU path) =========================
#define BM 32
#define BN 64
#define BD 32
#define LDP (BD + 4)

__global__ __launch_bounds__(256)
void sumsq_kernel(const float* __restrict__ x, const float* __restrict__ cb,
                  float* __restrict__ x_sq, float* __restrict__ e_sq) {
  int gwave = (blockIdx.x * 256 + threadIdx.x) >> 6;
  int lane  = threadIdx.x & 63;
  const float* src; float* dst;
  if (gwave < M) { src = x + (size_t)gwave * D; dst = x_sq + gwave; }
  else           { src = cb + (size_t)(gwave - M) * D; dst = e_sq + (gwave - M); }
  const float4* src4 = (const float4*)src;
  float s = 0.f;
#pragma unroll
  for (int i = 0; i < 2; ++i) {
    float4 v = src4[lane + i * 64];
    s += v.x * v.x + v.y * v.y + v.z * v.z + v.w * v.w;
  }
#pragma unroll
  for (int off = 32; off > 0; off >>= 1) s += __shfl_down(s, off, 64);
  if (lane == 0) *dst = s;
}

__global__ __launch_bounds__(256, 2)
void vq_argmin_gather(const float* __restrict__ x, const float* __restrict__ cb,
                      const float* __restrict__ values,
                      const float* __restrict__ x_sq, const float* __restrict__ e_sq,
                      float* __restrict__ out) {
  __shared__ float x_lds[BM][LDP];
  __shared__ float e_lds[BN][LDP];
  __shared__ float red_d[BM][17];
  __shared__ int   red_i[BM][17];
  __shared__ int   bestk[BM];
  const int tid = threadIdx.x;
  const int tx = tid & 15, ty = tid >> 4;
  const int r0 = blockIdx.x * BM, row0 = ty * 2;
  float xsqr[2] = {x_sq[r0 + row0], x_sq[r0 + row0 + 1]};
  float bd[2] = {FLT_BIG, FLT_BIG};
  int bi[2] = {0, 0};
  for (int kc = 0; kc < NCODE; kc += BN) {
    float acc[2][4] = {{0.f,0.f,0.f,0.f},{0.f,0.f,0.f,0.f}};
    for (int ds_ = 0; ds_ < D; ds_ += BD) {
      __syncthreads();
      { int row = tid >> 3, c4 = tid & 7;
        *(float4*)&x_lds[row][c4*4] = *(const float4*)(x + (size_t)(r0+row)*D + ds_ + c4*4); }
#pragma unroll
      for (int u = 0; u < 2; ++u) {
        int g2 = tid + u * 256, er = g2 >> 3, ec4 = g2 & 7;
        *(float4*)&e_lds[er][ec4*4] = *(const float4*)(cb + (size_t)(kc+er)*D + ds_ + ec4*4);
      }
      __syncthreads();
#pragma unroll
      for (int dg = 0; dg < BD; dg += 4) {
        float4 xv0 = *(const float4*)&x_lds[row0][dg];
        float4 xv1 = *(const float4*)&x_lds[row0+1][dg];
        float4 ev[4];
#pragma unroll
        for (int j = 0; j < 4; ++j) ev[j] = *(const float4*)&e_lds[tx + 16*j][dg];
#pragma unroll
        for (int j = 0; j < 4; ++j) {
          acc[0][j] += xv0.x*ev[j].x; acc[0][j] += xv0.y*ev[j].y;
          acc[0][j] += xv0.z*ev[j].z; acc[0][j] += xv0.w*ev[j].w;
          acc[1][j] += xv1.x*ev[j].x; acc[1][j] += xv1.y*ev[j].y;
          acc[1][j] += xv1.z*ev[j].z; acc[1][j] += xv1.w*ev[j].w;
        }
      }
    }
#pragma unroll
    for (int j = 0; j < 4; ++j) {
      int code = kc + tx + 16*j;
      float es2 = e_sq[code];
#pragma unroll
      for (int i = 0; i < 2; ++i) {
        float dist = xsqr[i] - 2.0f*acc[i][j] + es2;
        if (dist < bd[i] || (dist == bd[i] && code < bi[i])) { bd[i] = dist; bi[i] = code; }
      }
    }
  }
  __syncthreads();
#pragma unroll
  for (int i = 0; i < 2; ++i) { red_d[row0+i][tx] = bd[i]; red_i[row0+i][tx] = bi[i]; }
  __syncthreads();
  if (tid < BM) {
    float b = red_d[tid][0]; int idx = red_i[tid][0];
#pragma unroll
    for (int t = 1; t < 16; ++t) {
      float dd = red_d[tid][t]; int ii = red_i[tid][t];
      if (dd < b || (dd == b && ii < idx)) { b = dd; idx = ii; }
    }
    bestk[tid] = idx;
  }
  __syncthreads();
#pragma unroll
  for (int u = 0; u < 16; ++u) {
    int f = u * 256 + tid, row = f >> 7, q = f & 127;
    *(float4*)(out + (size_t)(r0+row)*D + q*4) =
        *(const float4*)(values + (size_t)bestk[row]*D + q*4);
  }
}

// ============================================================================
extern "C" void kernel_launch(void* const* d_in, const int* in_sizes, int n_in,
                              void* d_out, int out_size, void* d_ws, size_t ws_size,
                              hipStream_t stream) {
  const float* x      = (const float*)d_in[0];
  const float* cb     = (const float*)d_in[1];
  const float* values = (const float*)d_in[2];
  float* out = (float*)d_out;

  const size_t A_BYTES = (size_t)M * KH * 2;        // 16 MB (tile-transposed)
  const size_t B_BYTES = (size_t)NCODE * KH * 2;    // 8 MB
  const size_t C_BYTES = (size_t)M * NB * 16;       // 16 MB
  const size_t E_BYTES = (size_t)NCODE * 4;         // 32 KB
  const size_t NEED = A_BYTES + B_BYTES + C_BYTES + E_BYTES;

  if (ws_size >= NEED) {
    char* base = (char*)d_ws;
    __hip_bfloat16* Apack = (__hip_bfloat16*)base;
    __hip_bfloat16* Bpack = (__hip_bfloat16*)(base + A_BYTES);
    float4* cand = (float4*)(base + A_BYTES + B_BYTES);
    float* e_sq  = (float*)(base + A_BYTES + B_BYTES + C_BYTES);

    prep_tile<<<M / 128, 256, 0, stream>>>(x, Apack);
    prep_tile<<<NCODE / 128, 256, 0, stream>>>(cb, Bpack);
    rowsumsq<<<NCODE / 4, 256, 0, stream>>>(cb, e_sq, NCODE);
    vq_gemm_top2<<<(M / 128) * NB, 256, 0, stream>>>(Apack, Bpack, e_sq, cand);
    vq_merge_rescore<<<M / 4, 256, 0, stream>>>(x, cb, values, e_sq, cand, out);
  } else {
    float* x_sq = (float*)d_ws;
    float* e_sq = x_sq + M;
    sumsq_kernel<<<(M + NCODE) / 4, 256, 0, stream>>>(x, cb, x_sq, e_sq);
    vq_argmin_gather<<<M / BM, 256, 0, stream>>>(x, cb, values, x_sq, e_sq, out);
  }
}

// Round 6
// 1048.959 us; speedup vs baseline: 3.8918x; 1.0639x over previous
//
#include <hip/hip_runtime.h>
#include <hip/hip_bf16.h>

// VectorQuantize: argmin_k ||x - e_k||^2 then gather values[k].
// R6: m97-regime GEMM — 1024 blocks (1/CU), A-tile (128 rows x K=512 bf16 =
// 128 KB) resident in dynamic LDS, B streamed through a 2x8KB double buffer as
// one flat 128-step pipeline (8 n-tiles x 16 k-steps). Swapped-operand MFMA
// (mfma(b,a)) puts codes in the register dim -> per-row top-2 epilogue is
// in-register + 2 shfl stages, emitted as sortable u64 keys (score|code, np
// tie semantics) straight to global. Merge: global top-4 of 256 keys/row ->
// exact f32 rescore -> gather values[best].

#define D      512
#define M      16384
#define NCODE  8192
#define KH     512
#define NB     64          // NCODE / 128

typedef float f32x4  __attribute__((ext_vector_type(4)));
typedef short bf16x8 __attribute__((ext_vector_type(8)));

#define FLT_BIG 3.402823466e38f
#define KMAX   0xFFFFFFFFFFFFFFFFull

__device__ __forceinline__ void gload16(const __hip_bfloat16* g, __hip_bfloat16* l) {
  __builtin_amdgcn_global_load_lds(
      (const __attribute__((address_space(1))) void*)g,
      (__attribute__((address_space(3))) void*)l, 16, 0, 0);
}

__device__ __forceinline__ unsigned long long score_key(float sc, int code) {
  unsigned int u = __float_as_uint(sc);
  unsigned int su = u ^ ((unsigned int)((int)u >> 31) | 0x80000000u);
  return ((unsigned long long)su << 32) | (unsigned int)code;
}

__device__ __forceinline__ void kins2(unsigned long long k,
                                      unsigned long long& k1, unsigned long long& k2) {
  if (k < k1) { k2 = k1; k1 = k; }
  else if (k < k2) { k2 = k; }
}

__device__ __forceinline__ void kins4(unsigned long long k,
    unsigned long long& k0, unsigned long long& k1,
    unsigned long long& k2, unsigned long long& k3) {
  if (k < k0)      { k3 = k2; k2 = k1; k1 = k0; k0 = k; }
  else if (k < k1) { k3 = k2; k2 = k1; k1 = k; }
  else if (k < k2) { k3 = k2; k2 = k; }
  else if (k < k3) { k3 = k; }
}

__device__ __forceinline__ void top2_insert(float d, int i,
                                            float& d1, int& i1, float& d2, int& i2) {
  bool lt1 = (d < d1) || (d == d1 && i < i1);
  bool lt2 = (d < d2) || (d == d2 && i < i2);
  if (lt1) { d2 = d1; i2 = i1; d1 = d; i1 = i; }
  else if (lt2) { d2 = d; i2 = i; }
}

__device__ __forceinline__ void top4_insert(float nd, int ni,
    float& d0, int& i0, float& d1, int& i1,
    float& d2, int& i2, float& d3, int& i3) {
  bool l0 = (nd < d0) || (nd == d0 && ni < i0);
  bool l1 = (nd < d1) || (nd == d1 && ni < i1);
  bool l2 = (nd < d2) || (nd == d2 && ni < i2);
  bool l3 = (nd < d3) || (nd == d3 && ni < i3);
  if (l0)      { d3 = d2; i3 = i2; d2 = d1; i2 = i1; d1 = d0; i1 = i0; d0 = nd; i0 = ni; }
  else if (l1) { d3 = d2; i3 = i2; d2 = d1; i2 = i1; d1 = nd; i1 = ni; }
  else if (l2) { d3 = d2; i3 = i2; d2 = nd; i2 = ni; }
  else if (l3) { d3 = nd; i3 = ni; }
}

// ---- 1. f32 -> hi-bf16 tile-transposed pack (unchanged from R5) -------------
__global__ __launch_bounds__(256)
void prep_tile(const float* __restrict__ src, __hip_bfloat16* __restrict__ dst) {
  __shared__ __hip_bfloat16 tile[128][136];
  const int tid = threadIdx.x;
  const float* srow = src + (size_t)blockIdx.x * 128 * D;
  __hip_bfloat16* dbase = dst + (size_t)blockIdx.x * 64 * 128 * 8;

#pragma unroll 1
  for (int c = 0; c < 4; ++c) {
    __syncthreads();
#pragma unroll
    for (int j = 0; j < 8; ++j) {
      int f = tid + j * 256;
      int row = f >> 4, k16l = f & 15;
      const float4* p = (const float4*)(srow + (size_t)row * D + c * 128 + k16l * 8);
      float4 v0 = p[0], v1 = p[1];
      float vv[8] = {v0.x, v0.y, v0.z, v0.w, v1.x, v1.y, v1.z, v1.w};
      union { bf16x8 v; unsigned short u[8]; } pk;
#pragma unroll
      for (int e = 0; e < 8; ++e) {
        __hip_bfloat16 h = __float2bfloat16(vv[e]);
        pk.u[e] = *(unsigned short*)&h;
      }
      *(bf16x8*)&tile[row][k16l * 8] = pk.v;
    }
    __syncthreads();
#pragma unroll
    for (int j = 0; j < 8; ++j) {
      int g = tid + j * 256;
      int row = g & 127, k16l = g >> 7;
      bf16x8 v = *(const bf16x8*)&tile[row][k16l * 8];
      *(bf16x8*)(dbase + ((size_t)(c * 16 + k16l) * 128 + row) * 8) = v;
    }
  }
}

// ---- 2. exact f32 row sum-of-squares ----------------------------------------
__global__ __launch_bounds__(256)
void rowsumsq(const float* __restrict__ src, float* __restrict__ dst, int nrows) {
  int gw = (blockIdx.x * 256 + threadIdx.x) >> 6;
  if (gw >= nrows) return;
  int lane = threadIdx.x & 63;
  const float4* s4 = (const float4*)(src + (size_t)gw * D);
  float s = 0.f;
#pragma unroll
  for (int i = 0; i < 2; ++i) {
    float4 v = s4[lane + i * 64];
    s += v.x * v.x + v.y * v.y + v.z * v.z + v.w * v.w;
  }
#pragma unroll
  for (int off = 32; off > 0; off >>= 1) s += __shfl_down(s, off, 64);
  if (lane == 0) dst[gw] = s;
}

// ---- 3. A-resident 128-step pipelined GEMM + key epilogue -------------------
// Block: 128 rows x 1024 cols (8 n-tiles). 512 threads = 8 waves (2Mx4N).
// Wave tile: 64 rows x 32 codes via swapped mfma(b, a):
//   acc[nc][m][q] -> code = wc*32+nc*16+lh*4+q, row = wr*64+m*16+lr.
__global__ __launch_bounds__(512, 1)
void vq_gemm_a128(const __hip_bfloat16* __restrict__ Apack,
                  const __hip_bfloat16* __restrict__ Bpack,
                  const float* __restrict__ e_sq,
                  ulonglong2* __restrict__ cand2) {
  extern __shared__ __hip_bfloat16 smem[];
  __hip_bfloat16* A_l = smem;                       // 8192 granules = 128 KB
  __hip_bfloat16* B0  = smem + 65536;               // 512 granules = 8 KB
  __hip_bfloat16* B1  = smem + 65536 + 4096;        // 8 KB

  const int tid = threadIdx.x;
  const int w = tid >> 6, l = tid & 63;
  const int wr = w >> 2, wc = w & 3;                // 2 x 4 wave grid
  const int lr = l & 15, lh = l >> 4;

  // L2-aware: mt pinned to XCD, ntg slow so concurrent blocks share B chunk.
  const int bid = blockIdx.x;
  const int xcd = bid & 7, idx = bid >> 3;          // 128 blocks per XCD
  const int ntg = idx >> 4;                         // 8 n-groups (slow)
  const int mtl = idx & 15;
  const int mt = xcd * 16 + mtl;

  const __hip_bfloat16* Abase = Apack + (size_t)mt * 8192 * 8;
  const __hip_bfloat16* Bg8   = Bpack + (size_t)ntg * 8 * 8192 * 8;

  // prologue: A fully resident + B step 0
#pragma unroll
  for (int i = 0; i < 16; ++i)
    gload16(Abase + (size_t)(i * 512 + tid) * 8, A_l + (i * 512 + tid) * 8);
  gload16(Bg8 + (size_t)tid * 8, B0 + (size_t)tid * 8);
  __syncthreads();

#define STAGE(dst, u)                                                          \
  gload16(Bg8 + (size_t)((u) * 512 + tid) * 8, (dst) + (size_t)tid * 8)

#define COMPUTE(Bptr, t)                                                       \
  do {                                                                         \
    const bf16x8* Ag = (const bf16x8*)A_l + (t) * 512;                         \
    const bf16x8* Bgr = (const bf16x8*)(Bptr);                                 \
    bf16x8 bb[2], aa[4];                                                       \
    _Pragma("unroll")                                                          \
    for (int nc = 0; nc < 2; ++nc) bb[nc] = Bgr[lh * 128 + wc * 32 + nc * 16 + lr]; \
    _Pragma("unroll")                                                          \
    for (int m = 0; m < 4; ++m) aa[m] = Ag[lh * 128 + wr * 64 + m * 16 + lr];  \
    _Pragma("unroll")                                                          \
    for (int nc = 0; nc < 2; ++nc)                                             \
      _Pragma("unroll")                                                        \
      for (int m = 0; m < 4; ++m)                                              \
        acc[nc][m] = __builtin_amdgcn_mfma_f32_16x16x32_bf16(bb[nc], aa[m], acc[nc][m], 0, 0, 0); \
  } while (0)

#pragma unroll 1
  for (int j = 0; j < 8; ++j) {
    f32x4 acc[2][4] = {};
#pragma unroll 1
    for (int th = 0; th < 8; ++th) {
      const int t0 = th * 2, t1 = th * 2 + 1;
      const int u0 = j * 16 + t0, u1 = j * 16 + t1;
      {
        if (u0 + 1 < 128) STAGE(B1, u0 + 1);
        COMPUTE(B0, t0);
        __syncthreads();
      }
      {
        if (u1 + 1 < 128) STAGE(B0, u1 + 1);
        COMPUTE(B1, t1);
        __syncthreads();
      }
    }

    // ---- epilogue for n-tile j: per-row top-2 keys, no barriers ----
    const int nt = ntg * 8 + j;
    const int col0 = nt * 128;
    float4 es0 = *(const float4*)&e_sq[col0 + wc * 32 + lh * 4];
    float4 es1 = *(const float4*)&e_sq[col0 + wc * 32 + 16 + lh * 4];
    float e0v[4] = {es0.x, es0.y, es0.z, es0.w};
    float e1v[4] = {es1.x, es1.y, es1.z, es1.w};
#pragma unroll
    for (int m = 0; m < 4; ++m) {
      unsigned long long k1 = KMAX, k2 = KMAX;
#pragma unroll
      for (int q = 0; q < 4; ++q) {
        int c0 = col0 + wc * 32 + lh * 4 + q;
        kins2(score_key(e0v[q] - 2.0f * acc[0][m][q], c0), k1, k2);
        kins2(score_key(e1v[q] - 2.0f * acc[1][m][q], c0 + 16), k1, k2);
      }
#pragma unroll
      for (int s = 16; s <= 32; s <<= 1) {
        unsigned long long o1 = __shfl_xor(k1, s, 64);
        unsigned long long o2 = __shfl_xor(k2, s, 64);
        kins2(o1, k1, k2);
        kins2(o2, k1, k2);
      }
      if (lh == 0) {
        int gRow = mt * 128 + wr * 64 + m * 16 + lr;
        cand2[(size_t)gRow * 256 + nt * 4 + wc] = make_ulonglong2(k1, k2);
      }
    }
  }
#undef STAGE
#undef COMPUTE
}

// ---- 4. global top-4 over 256 keys/row, exact f32 rescore, gather -----------
__global__ __launch_bounds__(256)
void vq_merge4(const float* __restrict__ x, const float* __restrict__ cb,
               const float* __restrict__ values, const float* __restrict__ e_sq,
               const ulonglong2* __restrict__ cand2, float* __restrict__ out) {
  int row = blockIdx.x * 4 + (threadIdx.x >> 6);
  int l = threadIdx.x & 63;

  unsigned long long k0 = KMAX, k1 = KMAX, k2 = KMAX, k3 = KMAX;
  const ulonglong2* base = cand2 + (size_t)row * 256;
#pragma unroll
  for (int u = 0; u < 4; ++u) {
    ulonglong2 e = base[l + 64 * u];
    kins4(e.x, k0, k1, k2, k3);
    kins4(e.y, k0, k1, k2, k3);
  }
#pragma unroll
  for (int s = 1; s < 64; s <<= 1) {
    unsigned long long o0 = __shfl_xor(k0, s, 64), o1 = __shfl_xor(k1, s, 64);
    unsigned long long o2 = __shfl_xor(k2, s, 64), o3 = __shfl_xor(k3, s, 64);
    kins4(o0, k0, k1, k2, k3); kins4(o1, k0, k1, k2, k3);
    kins4(o2, k0, k1, k2, k3); kins4(o3, k0, k1, k2, k3);
  }
  int i0 = (int)(k0 & 8191), i1 = (int)(k1 & 8191);
  int i2 = (int)(k2 & 8191), i3 = (int)(k3 & 8191);

  // exact f32 rescore (deterministic order)
  const float4* xr = (const float4*)(x + (size_t)row * D);
  const float4* c0 = (const float4*)(cb + (size_t)i0 * D);
  const float4* c1 = (const float4*)(cb + (size_t)i1 * D);
  const float4* c2 = (const float4*)(cb + (size_t)i2 * D);
  const float4* c3 = (const float4*)(cb + (size_t)i3 * D);
  float xsq = 0.f, t0 = 0.f, t1 = 0.f, t2 = 0.f, t3 = 0.f;
#pragma unroll
  for (int u = 0; u < 2; ++u) {
    float4 xv = xr[l + 64 * u];
    float4 a = c0[l + 64 * u], b = c1[l + 64 * u];
    float4 c = c2[l + 64 * u], e = c3[l + 64 * u];
    xsq += xv.x * xv.x + xv.y * xv.y + xv.z * xv.z + xv.w * xv.w;
    t0 += xv.x * a.x + xv.y * a.y + xv.z * a.z + xv.w * a.w;
    t1 += xv.x * b.x + xv.y * b.y + xv.z * b.z + xv.w * b.w;
    t2 += xv.x * c.x + xv.y * c.y + xv.z * c.z + xv.w * c.w;
    t3 += xv.x * e.x + xv.y * e.y + xv.z * e.z + xv.w * e.w;
  }
#pragma unroll
  for (int s = 1; s < 64; s <<= 1) {
    xsq += __shfl_xor(xsq, s, 64);
    t0 += __shfl_xor(t0, s, 64); t1 += __shfl_xor(t1, s, 64);
    t2 += __shfl_xor(t2, s, 64); t3 += __shfl_xor(t3, s, 64);
  }
  float D0 = xsq - 2.0f * t0 + e_sq[i0];
  float D1 = xsq - 2.0f * t1 + e_sq[i1];
  float D2 = xsq - 2.0f * t2 + e_sq[i2];
  float D3 = xsq - 2.0f * t3 + e_sq[i3];
  float bdist = D0; int best = i0;
  if (D1 < bdist || (D1 == bdist && i1 < best)) { bdist = D1; best = i1; }
  if (D2 < bdist || (D2 == bdist && i2 < best)) { bdist = D2; best = i2; }
  if (D3 < bdist || (D3 == bdist && i3 < best)) { bdist = D3; best = i3; }

  const float4* vsrc = (const float4*)(values + (size_t)best * D);
  float4* dst = (float4*)(out + (size_t)row * D);
  dst[l] = vsrc[l];
  dst[l + 64] = vsrc[l + 64];
}

// ================= R5 fallback path (proven 1116 us) =========================
__global__ __launch_bounds__(256, 3)
void vq_gemm_top2(const __hip_bfloat16* __restrict__ Apack,
                  const __hip_bfloat16* __restrict__ Bpack,
                  const float* __restrict__ e_sq,
                  float4* __restrict__ cand) {
  __shared__ __hip_bfloat16 As[2][128 * 32];
  __shared__ __hip_bfloat16 Bs[2][128 * 32];
  __shared__ float4 red[128][2];

  const int tid = threadIdx.x;
  const int w = tid >> 6, l = tid & 63;
  const int wr = w >> 1, wc = w & 1;
  const int lr = l & 15, lh = l >> 4;

  const int bid = blockIdx.x;
  const int xcd = bid & 7, idx = bid >> 3;
  const int g = idx >> 7;
  const int rem = idx & 127;
  const int mtl = rem >> 3, ntl = rem & 7;
  const int mt = xcd * 16 + mtl;
  const int nt = g * 8 + ntl;
  const int col0 = nt * 128;

  f32x4 acc[4][4] = {};
  const int f0 = tid, f1 = tid + 256;
  const __hip_bfloat16* Abase = Apack + (size_t)mt * 64 * 128 * 8;
  const __hip_bfloat16* Bbase = Bpack + (size_t)nt * 64 * 128 * 8;

#define STAGE5(buf, t)                                                     \
  do {                                                                     \
    gload16(Abase + ((size_t)(t) * 512 + f0) * 8, As[(buf)] + f0 * 8);     \
    gload16(Abase + ((size_t)(t) * 512 + f1) * 8, As[(buf)] + f1 * 8);     \
    gload16(Bbase + ((size_t)(t) * 512 + f0) * 8, Bs[(buf)] + f0 * 8);     \
    gload16(Bbase + ((size_t)(t) * 512 + f1) * 8, Bs[(buf)] + f1 * 8);     \
  } while (0)

#define COMPUTE5(buf)                                                            \
  do {                                                                           \
    const bf16x8* Ag = (const bf16x8*)As[(buf)];                                 \
    const bf16x8* Bg = (const bf16x8*)Bs[(buf)];                                 \
    bf16x8 a[4], b[4];                                                           \
    _Pragma("unroll")                                                            \
    for (int m = 0; m < 4; ++m) a[m] = Ag[lh * 128 + wr * 64 + m * 16 + lr];     \
    _Pragma("unroll")                                                            \
    for (int n = 0; n < 4; ++n) b[n] = Bg[lh * 128 + wc * 64 + n * 16 + lr];     \
    _Pragma("unroll")                                                            \
    for (int m = 0; m < 4; ++m)                                                  \
      _Pragma("unroll")                                                          \
      for (int n = 0; n < 4; ++n)                                                \
        acc[m][n] = __builtin_amdgcn_mfma_f32_16x16x32_bf16(a[m], b[n], acc[m][n], 0, 0, 0); \
  } while (0)

  STAGE5(0, 0);
  __syncthreads();
#pragma unroll 1
  for (int t = 0; t < 15; ++t) {
    const int cur = t & 1;
    STAGE5(cur ^ 1, t + 1);
    COMPUTE5(cur);
    __syncthreads();
  }
  COMPUTE5(1);
#undef STAGE5
#undef COMPUTE5

  float es[4];
#pragma unroll
  for (int n = 0; n < 4; ++n) es[n] = e_sq[col0 + wc * 64 + n * 16 + lr];
#pragma unroll
  for (int m = 0; m < 4; ++m) {
#pragma unroll
    for (int q = 0; q < 4; ++q) {
      float d1 = FLT_BIG, d2 = FLT_BIG;
      int   i1 = 0x7fffffff, i2 = 0x7fffffff;
#pragma unroll
      for (int n = 0; n < 4; ++n) {
        int cl = wc * 64 + n * 16 + lr;
        float sc = es[n] - 2.0f * acc[m][n][q];
        top2_insert(sc, col0 + cl, d1, i1, d2, i2);
      }
#pragma unroll
      for (int s2 = 1; s2 < 16; s2 <<= 1) {
        float od1 = __shfl_xor(d1, s2, 64); int oi1 = __shfl_xor(i1, s2, 64);
        float od2 = __shfl_xor(d2, s2, 64); int oi2 = __shfl_xor(i2, s2, 64);
        top2_insert(od1, oi1, d1, i1, d2, i2);
        top2_insert(od2, oi2, d1, i1, d2, i2);
      }
      if (lr == 0)
        red[wr * 64 + m * 16 + lh * 4 + q][wc] =
            make_float4(d1, __int_as_float(i1), d2, __int_as_float(i2));
    }
  }
  __syncthreads();
  if (tid < 128) {
    float4 r0 = red[tid][0], r1 = red[tid][1];
    float d1 = r0.x; int i1 = __float_as_int(r0.y);
    float d2 = r0.z; int i2 = __float_as_int(r0.w);
    top2_insert(r1.x, __float_as_int(r1.y), d1, i1, d2, i2);
    top2_insert(r1.z, __float_as_int(r1.w), d1, i1, d2, i2);
    cand[(size_t)(mt * 128 + tid) * NB + nt] =
        make_float4(d1, __int_as_float(i1), d2, __int_as_float(i2));
  }
}

__global__ __launch_bounds__(256)
void vq_merge_rescore(const float* __restrict__ x, const float* __restrict__ cb,
                      const float* __restrict__ values, const float* __restrict__ e_sq,
                      const float4* __restrict__ cand, float* __restrict__ out) {
  int row = blockIdx.x * 4 + (threadIdx.x >> 6);
  int l = threadIdx.x & 63;

  float4 rec = cand[(size_t)row * NB + l];
  float d0 = rec.x, d1 = rec.z, d2 = FLT_BIG, d3 = FLT_BIG;
  int i0 = __float_as_int(rec.y), i1 = __float_as_int(rec.w);
  int i2 = 0x7fffffff, i3 = 0x7fffffff;
#pragma unroll
  for (int s2 = 1; s2 < 64; s2 <<= 1) {
    float e0 = __shfl_xor(d0, s2, 64), e1 = __shfl_xor(d1, s2, 64);
    float e2 = __shfl_xor(d2, s2, 64), e3 = __shfl_xor(d3, s2, 64);
    int   j0 = __shfl_xor(i0, s2, 64), j1 = __shfl_xor(i1, s2, 64);
    int   j2 = __shfl_xor(i2, s2, 64), j3 = __shfl_xor(i3, s2, 64);
    top4_insert(e0, j0, d0, i0, d1, i1, d2, i2, d3, i3);
    top4_insert(e1, j1, d0, i0, d1, i1, d2, i2, d3, i3);
    top4_insert(e2, j2, d0, i0, d1, i1, d2, i2, d3, i3);
    top4_insert(e3, j3, d0, i0, d1, i1, d2, i2, d3, i3);
  }
  i0 &= 8191; i1 &= 8191; i2 &= 8191; i3 &= 8191;

  const float4* c0 = (const float4*)(cb + (size_t)i0 * D);
  const float4* c1 = (const float4*)(cb + (size_t)i1 * D);
  const float4* c2 = (const float4*)(cb + (size_t)i2 * D);
  const float4* c3 = (const float4*)(cb + (size_t)i3 * D);
  const float4* xr = (const float4*)(x + (size_t)row * D);
  float xsq = 0.f, t0 = 0.f, t1 = 0.f, t2 = 0.f, t3 = 0.f;
#pragma unroll
  for (int u = 0; u < 2; ++u) {
    float4 xv = xr[l + 64 * u];
    float4 a = c0[l + 64 * u], b = c1[l + 64 * u];
    float4 c = c2[l + 64 * u], e = c3[l + 64 * u];
    xsq += xv.x * xv.x + xv.y * xv.y + xv.z * xv.z + xv.w * xv.w;
    t0 += xv.x * a.x + xv.y * a.y + xv.z * a.z + xv.w * a.w;
    t1 += xv.x * b.x + xv.y * b.y + xv.z * b.z + xv.w * b.w;
    t2 += xv.x * c.x + xv.y * c.y + xv.z * c.z + xv.w * c.w;
    t3 += xv.x * e.x + xv.y * e.y + xv.z * e.z + xv.w * e.w;
  }
#pragma unroll
  for (int s2 = 1; s2 < 64; s2 <<= 1) {
    xsq += __shfl_xor(xsq, s2, 64);
    t0 += __shfl_xor(t0, s2, 64); t1 += __shfl_xor(t1, s2, 64);
    t2 += __shfl_xor(t2, s2, 64); t3 += __shfl_xor(t3, s2, 64);
  }
  float D0 = xsq - 2.0f * t0 + e_sq[i0];
  float D1 = xsq - 2.0f * t1 + e_sq[i1];
  float D2 = xsq - 2.0f * t2 + e_sq[i2];
  float D3 = xsq - 2.0f * t3 + e_sq[i3];
  float bdist = D0; int best = i0;
  if (D1 < bdist || (D1 == bdist && i1 < best)) { bdist = D1; best = i1; }
  if (D2 < bdist || (D2 == bdist && i2 < best)) { bdist = D2; best = i2; }
  if (D3 < bdist || (D3 == bdist && i3 < best)) { bdist = D3; best = i3; }

  const float4* vsrc = (const float4*)(values + (size_t)best * D);
  float4* dst = (float4*)(out + (size_t)row * D);
  dst[l] = vsrc[l];
  dst[l + 64] = vsrc[l + 64];
}

// ============================================================================
extern "C" void kernel_launch(void* const* d_in, const int* in_sizes, int n_in,
                              void* d_out, int out_size, void* d_ws, size_t ws_size,
                              hipStream_t stream) {
  const float* x      = (const float*)d_in[0];
  const float* cb     = (const float*)d_in[1];
  const float* values = (const float*)d_in[2];
  float* out = (float*)d_out;

  const size_t A_BYTES  = (size_t)M * KH * 2;          // 16 MB
  const size_t B_BYTES  = (size_t)NCODE * KH * 2;      // 8 MB
  const size_t C2_BYTES = (size_t)M * 256 * 16;        // 64 MB (u64-key pairs)
  const size_t C5_BYTES = (size_t)M * NB * 16;         // 16 MB (R5 cand)
  const size_t E_BYTES  = (size_t)NCODE * 4;
  const size_t NEED_NEW = A_BYTES + B_BYTES + C2_BYTES + E_BYTES;   // ~88 MB
  const size_t NEED_R5  = A_BYTES + B_BYTES + C5_BYTES + E_BYTES;   // ~40 MB

  const int LDS_NEW = 147456;   // 128 KB A + 2 x 8 KB B

  bool use_new = ws_size >= NEED_NEW;
  if (use_new) {
    hipError_t e = hipFuncSetAttribute(
        reinterpret_cast<const void*>(vq_gemm_a128),
        hipFuncAttributeMaxDynamicSharedMemorySize, LDS_NEW);
    use_new = (e == hipSuccess);
  }

  char* base = (char*)d_ws;
  __hip_bfloat16* Apack = (__hip_bfloat16*)base;
  __hip_bfloat16* Bpack = (__hip_bfloat16*)(base + A_BYTES);

  if (use_new) {
    ulonglong2* cand2 = (ulonglong2*)(base + A_BYTES + B_BYTES);
    float* e_sq = (float*)(base + A_BYTES + B_BYTES + C2_BYTES);

    prep_tile<<<M / 128, 256, 0, stream>>>(x, Apack);
    prep_tile<<<NCODE / 128, 256, 0, stream>>>(cb, Bpack);
    rowsumsq<<<NCODE / 4, 256, 0, stream>>>(cb, e_sq, NCODE);
    vq_gemm_a128<<<1024, 512, LDS_NEW, stream>>>(Apack, Bpack, e_sq, cand2);
    vq_merge4<<<M / 4, 256, 0, stream>>>(x, cb, values, e_sq, cand2, out);
  } else {
    float4* cand = (float4*)(base + A_BYTES + B_BYTES);
    float* e_sq  = (float*)(base + A_BYTES + B_BYTES + C5_BYTES);

    prep_tile<<<M / 128, 256, 0, stream>>>(x, Apack);
    prep_tile<<<NCODE / 128, 256, 0, stream>>>(cb, Bpack);
    rowsumsq<<<NCODE / 4, 256, 0, stream>>>(cb, e_sq, NCODE);
    vq_gemm_top2<<<(M / 128) * NB, 256, 0, stream>>>(Apack, Bpack, e_sq, cand);
    vq_merge_rescore<<<M / 4, 256, 0, stream>>>(x, cb, values, e_sq, cand, out);
  }
}

// Round 7
// 779.326 us; speedup vs baseline: 5.2382x; 1.3460x over previous
//
#include <hip/hip_runtime.h>
#include <hip/hip_bf16.h>

// VectorQuantize: argmin_k ||x - e_k||^2 then gather values[k].
// R7: hi-bf16 candidate GEMM in 256x256-tile / BK=64 form (64 MFMA per wave
// per barrier -- amortizes the ~1-3.7k-cycle per-barrier overhead measured in
// R2-R6), plain 2-phase double buffer, swapped-operand MFMA epilogue emitting
// per-row top-2 sortable keys, global top-4 -> exact f32 rescore (np tie
// semantics) -> gather values[best].
//
// Pack layout: P[tile256][k16 0..63][row 0..255][8] bf16. K-step t stages
// k16 = 8t..8t+7 (A and B slabs each 2048 granules = 32 KB), granule index
// f = (kk*4+lh)*256 + row is identical in global and LDS -> gload_lds is
// lane-linear. prep chunk c == GEMM step t (both cover 64 columns).

#define D      512
#define M      16384
#define NCODE  8192
#define KH     512
#define NSTEP  8           // K-steps of BK=64
#define TILEG  131072      // elems per 256-row tile (256*512)

typedef float f32x4  __attribute__((ext_vector_type(4)));
typedef short bf16x8 __attribute__((ext_vector_type(8)));

#define KMAX 0xFFFFFFFFFFFFFFFFull

__device__ __forceinline__ void gload16(const __hip_bfloat16* g, __hip_bfloat16* l) {
  __builtin_amdgcn_global_load_lds(
      (const __attribute__((address_space(1))) void*)g,
      (__attribute__((address_space(3))) void*)l, 16, 0, 0);
}

__device__ __forceinline__ unsigned long long score_key(float sc, int code) {
  unsigned int u = __float_as_uint(sc);
  unsigned int su = u ^ ((unsigned int)((int)u >> 31) | 0x80000000u);
  return ((unsigned long long)su << 32) | (unsigned int)code;
}

__device__ __forceinline__ void kins2(unsigned long long k,
                                      unsigned long long& k1, unsigned long long& k2) {
  if (k < k1) { k2 = k1; k1 = k; }
  else if (k < k2) { k2 = k; }
}

__device__ __forceinline__ void kins4(unsigned long long k,
    unsigned long long& k0, unsigned long long& k1,
    unsigned long long& k2, unsigned long long& k3) {
  if (k < k0)      { k3 = k2; k2 = k1; k1 = k0; k0 = k; }
  else if (k < k1) { k3 = k2; k2 = k1; k1 = k; }
  else if (k < k2) { k3 = k2; k2 = k; }
  else if (k < k3) { k3 = k; }
}

// ---- 1. f32 -> hi-bf16 256-row tile-transposed pack -------------------------
// Grid: (nrows/256) * 8 chunks. Block 256. Chunk c covers cols c*64..c*64+63
// (k16l = 0..7 local granule-column).
__global__ __launch_bounds__(256)
void prep256(const float* __restrict__ src, __hip_bfloat16* __restrict__ dst) {
  __shared__ __hip_bfloat16 tile[256][72];   // 36 KB, padded row (144 B)
  const int tid = threadIdx.x;
  const int c = blockIdx.x & 7, t = blockIdx.x >> 3;
  const float* srow = src + (size_t)t * 256 * D;
  __hip_bfloat16* dbase = dst + (size_t)t * TILEG;

#pragma unroll
  for (int j = 0; j < 8; ++j) {
    int f = tid + j * 256;                 // 2048 granules: row = f>>3, k16l = f&7
    int row = f >> 3, k16l = f & 7;
    const float4* p = (const float4*)(srow + (size_t)row * D + c * 64 + k16l * 8);
    float4 v0 = p[0], v1 = p[1];
    float vv[8] = {v0.x, v0.y, v0.z, v0.w, v1.x, v1.y, v1.z, v1.w};
    union { bf16x8 v; unsigned short u[8]; } pk;
#pragma unroll
    for (int e = 0; e < 8; ++e) {
      __hip_bfloat16 h = __float2bfloat16(vv[e]);   // RNE
      pk.u[e] = *(unsigned short*)&h;
    }
    *(bf16x8*)&tile[row][k16l * 8] = pk.v;
  }
  __syncthreads();
#pragma unroll
  for (int j = 0; j < 8; ++j) {
    int g = tid + j * 256;                 // out granule: row = g&255, k16l = g>>8
    int row = g & 255, k16l = g >> 8;
    bf16x8 v = *(const bf16x8*)&tile[row][k16l * 8];
    *(bf16x8*)(dbase + ((size_t)(c * 8 + k16l) * 256 + row) * 8) = v;
  }
}

// ---- 2. exact f32 row sum-of-squares (codebook) -----------------------------
__global__ __launch_bounds__(256)
void rowsumsq(const float* __restrict__ src, float* __restrict__ dst, int nrows) {
  int gw = (blockIdx.x * 256 + threadIdx.x) >> 6;
  if (gw >= nrows) return;
  int lane = threadIdx.x & 63;
  const float4* s4 = (const float4*)(src + (size_t)gw * D);
  float s = 0.f;
#pragma unroll
  for (int i = 0; i < 2; ++i) {
    float4 v = s4[lane + i * 64];
    s += v.x * v.x + v.y * v.y + v.z * v.z + v.w * v.w;
  }
#pragma unroll
  for (int off = 32; off > 0; off >>= 1) s += __shfl_down(s, off, 64);
  if (lane == 0) dst[gw] = s;
}

// ---- 3. 256x256-tile BK=64 GEMM, 2-phase dbuf, per-wave top-2 keys ----------
// 512 threads = 8 waves (wr in {0,1} x wc in {0..3}). Wave tile: 128 rows x
// 64 codes. Swapped mfma(b, a): acc[nc][m][q] -> code = ct*256 + wc*64 +
// nc*16 + lh*4 + q, row = mt*256 + wr*128 + m*16 + lr.
__global__ __launch_bounds__(512, 1)
void vq_gemm256(const __hip_bfloat16* __restrict__ Apack,
                const __hip_bfloat16* __restrict__ Bpack,
                const float* __restrict__ e_sq,
                ulonglong2* __restrict__ cand2) {
  extern __shared__ __hip_bfloat16 smem[];
  // granule map (16 B each): buf*4096 + {A: 0..2047, B: 2048..4095}

  const int tid = threadIdx.x;
  const int w = tid >> 6, l = tid & 63;
  const int wr = w >> 2, wc = w & 3;
  const int lr = l & 15, lh = l >> 4;

  // L2-aware ordering: per XCD an 8-mt stripe, ct sweeps slowly.
  const int bid = blockIdx.x;
  const int xcd = bid & 7, idx = bid >> 3;   // 256 blocks per XCD
  const int mt = xcd * 8 + (idx & 7);        // 64 m-tiles
  const int ct = idx >> 3;                   // 32 c-tiles

  const __hip_bfloat16* Abase = Apack + (size_t)mt * TILEG;
  const __hip_bfloat16* Bbase = Bpack + (size_t)ct * TILEG;

  f32x4 acc[4][8] = {};

#define STAGE(buf, t)                                                           \
  do {                                                                          \
    _Pragma("unroll")                                                           \
    for (int i = 0; i < 4; ++i) {                                               \
      const int g = tid + i * 512;                                              \
      gload16(Abase + ((size_t)(t) * 2048 + g) * 8,                             \
              smem + ((size_t)(buf) * 4096 + g) * 8);                           \
      gload16(Bbase + ((size_t)(t) * 2048 + g) * 8,                             \
              smem + ((size_t)(buf) * 4096 + 2048 + g) * 8);                    \
    }                                                                           \
  } while (0)

#define COMPUTE(buf)                                                            \
  do {                                                                          \
    const bf16x8* Ag = (const bf16x8*)smem + (buf) * 4096;                      \
    const bf16x8* Bg = Ag + 2048;                                               \
    _Pragma("unroll")                                                           \
    for (int kk = 0; kk < 2; ++kk) {                                            \
      const int kb = (kk * 4 + lh) * 256;                                       \
      bf16x8 a[8], b[4];                                                        \
      _Pragma("unroll")                                                         \
      for (int nc = 0; nc < 4; ++nc) b[nc] = Bg[kb + wc * 64 + nc * 16 + lr];   \
      _Pragma("unroll")                                                         \
      for (int m = 0; m < 8; ++m)   a[m] = Ag[kb + wr * 128 + m * 16 + lr];     \
      _Pragma("unroll")                                                         \
      for (int nc = 0; nc < 4; ++nc)                                            \
        _Pragma("unroll")                                                       \
        for (int m = 0; m < 8; ++m)                                             \
          acc[nc][m] = __builtin_amdgcn_mfma_f32_16x16x32_bf16(b[nc], a[m],     \
                                                               acc[nc][m], 0, 0, 0); \
    }                                                                           \
  } while (0)

  STAGE(0, 0);
  __syncthreads();
#pragma unroll 1
  for (int t = 0; t < NSTEP - 1; ++t) {
    const int cur = t & 1;
    STAGE(cur ^ 1, t + 1);       // prefetch issued before compute
    COMPUTE(cur);
    __syncthreads();             // one barrier per step
  }
  COMPUTE((NSTEP - 1) & 1);
#undef STAGE
#undef COMPUTE

  // ---- epilogue: per-row top-2 keys over this wave's 64-code strip ----
  const int col0 = ct * 256 + wc * 64;
  float es[4][4];
#pragma unroll
  for (int nc = 0; nc < 4; ++nc) {
    float4 e4 = *(const float4*)&e_sq[col0 + nc * 16 + lh * 4];
    es[nc][0] = e4.x; es[nc][1] = e4.y; es[nc][2] = e4.z; es[nc][3] = e4.w;
  }
#pragma unroll
  for (int m = 0; m < 8; ++m) {
    unsigned long long k1 = KMAX, k2 = KMAX;
#pragma unroll
    for (int nc = 0; nc < 4; ++nc)
#pragma unroll
      for (int q = 0; q < 4; ++q) {
        int code = col0 + nc * 16 + lh * 4 + q;
        kins2(score_key(es[nc][q] - 2.0f * acc[nc][m][q], code), k1, k2);
      }
#pragma unroll
    for (int s = 16; s <= 32; s <<= 1) {     // reduce over lh (4 lanes per lr)
      unsigned long long o1 = __shfl_xor(k1, s, 64);
      unsigned long long o2 = __shfl_xor(k2, s, 64);
      kins2(o1, k1, k2);
      kins2(o2, k1, k2);
    }
    if (lh == 0) {
      int gRow = mt * 256 + wr * 128 + m * 16 + lr;
      cand2[(size_t)gRow * 128 + ct * 4 + wc] = make_ulonglong2(k1, k2);
    }
  }
}

// ---- 4. global top-4 over 256 keys/row, exact f32 rescore, gather -----------
__global__ __launch_bounds__(256)
void vq_merge4(const float* __restrict__ x, const float* __restrict__ cb,
               const float* __restrict__ values, const float* __restrict__ e_sq,
               const ulonglong2* __restrict__ cand2, float* __restrict__ out) {
  int row = blockIdx.x * 4 + (threadIdx.x >> 6);
  int l = threadIdx.x & 63;

  unsigned long long k0 = KMAX, k1 = KMAX, k2 = KMAX, k3 = KMAX;
  const ulonglong2* base = cand2 + (size_t)row * 128;
#pragma unroll
  for (int u = 0; u < 2; ++u) {
    ulonglong2 e = base[l + 64 * u];
    kins4(e.x, k0, k1, k2, k3);
    kins4(e.y, k0, k1, k2, k3);
  }
#pragma unroll
  for (int s = 1; s < 64; s <<= 1) {
    unsigned long long o0 = __shfl_xor(k0, s, 64), o1 = __shfl_xor(k1, s, 64);
    unsigned long long o2 = __shfl_xor(k2, s, 64), o3 = __shfl_xor(k3, s, 64);
    kins4(o0, k0, k1, k2, k3); kins4(o1, k0, k1, k2, k3);
    kins4(o2, k0, k1, k2, k3); kins4(o3, k0, k1, k2, k3);
  }
  int i0 = (int)(k0 & 8191), i1 = (int)(k1 & 8191);
  int i2 = (int)(k2 & 8191), i3 = (int)(k3 & 8191);

  // exact f32 rescore (deterministic order)
  const float4* xr = (const float4*)(x + (size_t)row * D);
  const float4* c0 = (const float4*)(cb + (size_t)i0 * D);
  const float4* c1 = (const float4*)(cb + (size_t)i1 * D);
  const float4* c2 = (const float4*)(cb + (size_t)i2 * D);
  const float4* c3 = (const float4*)(cb + (size_t)i3 * D);
  float xsq = 0.f, t0 = 0.f, t1 = 0.f, t2 = 0.f, t3 = 0.f;
#pragma unroll
  for (int u = 0; u < 2; ++u) {
    float4 xv = xr[l + 64 * u];
    float4 a = c0[l + 64 * u], b = c1[l + 64 * u];
    float4 c = c2[l + 64 * u], e = c3[l + 64 * u];
    xsq += xv.x * xv.x + xv.y * xv.y + xv.z * xv.z + xv.w * xv.w;
    t0 += xv.x * a.x + xv.y * a.y + xv.z * a.z + xv.w * a.w;
    t1 += xv.x * b.x + xv.y * b.y + xv.z * b.z + xv.w * b.w;
    t2 += xv.x * c.x + xv.y * c.y + xv.z * c.z + xv.w * c.w;
    t3 += xv.x * e.x + xv.y * e.y + xv.z * e.z + xv.w * e.w;
  }
#pragma unroll
  for (int s = 1; s < 64; s <<= 1) {
    xsq += __shfl_xor(xsq, s, 64);
    t0 += __shfl_xor(t0, s, 64); t1 += __shfl_xor(t1, s, 64);
    t2 += __shfl_xor(t2, s, 64); t3 += __shfl_xor(t3, s, 64);
  }
  float D0 = xsq - 2.0f * t0 + e_sq[i0];
  float D1 = xsq - 2.0f * t1 + e_sq[i1];
  float D2 = xsq - 2.0f * t2 + e_sq[i2];
  float D3 = xsq - 2.0f * t3 + e_sq[i3];
  float bdist = D0; int best = i0;
  if (D1 < bdist || (D1 == bdist && i1 < best)) { bdist = D1; best = i1; }
  if (D2 < bdist || (D2 == bdist && i2 < best)) { bdist = D2; best = i2; }
  if (D3 < bdist || (D3 == bdist && i3 < best)) { bdist = D3; best = i3; }

  const float4* vsrc = (const float4*)(values + (size_t)best * D);
  float4* dst = (float4*)(out + (size_t)row * D);
  dst[l] = vsrc[l];
  dst[l + 64] = vsrc[l + 64];
}

// ============================================================================
extern "C" void kernel_launch(void* const* d_in, const int* in_sizes, int n_in,
                              void* d_out, int out_size, void* d_ws, size_t ws_size,
                              hipStream_t stream) {
  const float* x      = (const float*)d_in[0];
  const float* cb     = (const float*)d_in[1];
  const float* values = (const float*)d_in[2];
  float* out = (float*)d_out;

  const size_t A_BYTES = (size_t)M * KH * 2;          // 16 MB
  const size_t B_BYTES = (size_t)NCODE * KH * 2;      // 8 MB
  const size_t C_BYTES = (size_t)M * 128 * 16;        // 32 MB (key pairs)

  char* base = (char*)d_ws;
  __hip_bfloat16* Apack = (__hip_bfloat16*)base;
  __hip_bfloat16* Bpack = (__hip_bfloat16*)(base + A_BYTES);
  ulonglong2* cand2 = (ulonglong2*)(base + A_BYTES + B_BYTES);
  float* e_sq = (float*)(base + A_BYTES + B_BYTES + C_BYTES);

  const int LDS_GEMM = 131072;   // 2 x (32 KB A + 32 KB B)
  (void)hipFuncSetAttribute(reinterpret_cast<const void*>(vq_gemm256),
                            hipFuncAttributeMaxDynamicSharedMemorySize, LDS_GEMM);

  prep256<<<(M / 256) * 8, 256, 0, stream>>>(x, Apack);
  prep256<<<(NCODE / 256) * 8, 256, 0, stream>>>(cb, Bpack);
  rowsumsq<<<NCODE / 4, 256, 0, stream>>>(cb, e_sq, NCODE);
  vq_gemm256<<<(M / 256) * (NCODE / 256), 512, LDS_GEMM, stream>>>(
      Apack, Bpack, e_sq, cand2);
  vq_merge4<<<M / 4, 256, 0, stream>>>(x, cb, values, e_sq, cand2, out);
}